// Round 3
// baseline (5826.181 us; speedup 1.0000x reference)
//
#include <hip/hip_runtime.h>
#include <hip/hip_bf16.h>

#define B_ 2
#define S_ 1024
#define D_ 768
#define H_ 12
#define HD_ 64
#define V_ 32000
#define NQ_ 768
#define NTOK (B_*S_)

// ---------------- embedding ----------------
__global__ void k_embed(const int* __restrict__ x, const float* __restrict__ emb,
                        float* __restrict__ h0) {
    int n = blockIdx.x;
    int row = x[n];
    for (int d = threadIdx.x; d < D_; d += blockDim.x)
        h0[(long)n*D_ + d] = emb[(long)row*D_ + d];
}

// ---------------- maxpool3 over sequence ----------------
__global__ void k_maxpool(const float* __restrict__ h0, float* __restrict__ mp) {
    int n = blockIdx.x; int s = n % S_;
    for (int d = threadIdx.x; d < D_; d += blockDim.x) {
        float m = h0[(long)n*D_ + d];
        if (s > 0)      m = fmaxf(m, h0[(long)(n-1)*D_ + d]);
        if (s < S_-1)   m = fmaxf(m, h0[(long)(n+1)*D_ + d]);
        mp[(long)n*D_ + d] = m;
    }
}

// ---------------- conv k=3 (96 -> 128), pad 1, writes h1 cols 64..191 ----------------
__global__ void k_conv3(const float* __restrict__ t3, const float* __restrict__ w,
                        const float* __restrict__ bias, float* __restrict__ h1) {
    __shared__ float sm[3][96];
    int n = blockIdx.x; int s = n % S_;
    int t = threadIdx.x;                   // 128 threads
    for (int idx = t; idx < 3*96; idx += 128) {
        int k = idx / 96, i = idx % 96;
        int ss = s + k - 1;
        sm[k][i] = (ss >= 0 && ss < S_) ? t3[(long)(n + k - 1)*96 + i] : 0.f;
    }
    __syncthreads();
    int o = t;
    float acc = bias[o];
    #pragma unroll
    for (int k = 0; k < 3; k++)
        for (int i = 0; i < 96; i++)
            acc += sm[k][i] * w[((o*96 + i)*3) + k];
    h1[(long)n*NQ_ + 64 + o] = acc;
}

// ---------------- conv k=5 (16 -> 32), pad 2, writes h1 cols 192..223 ----------------
__global__ void k_conv5(const float* __restrict__ t5, const float* __restrict__ w,
                        const float* __restrict__ bias, float* __restrict__ h1) {
    __shared__ float sm[5][16];
    int n = blockIdx.x; int s = n % S_;
    int t = threadIdx.x;                   // 64 threads
    for (int idx = t; idx < 5*16; idx += 64) {
        int k = idx / 16, i = idx % 16;
        int ss = s + k - 2;
        sm[k][i] = (ss >= 0 && ss < S_) ? t5[(long)(n + k - 2)*16 + i] : 0.f;
    }
    __syncthreads();
    if (t < 32) {
        float acc = bias[t];
        #pragma unroll
        for (int k = 0; k < 5; k++)
            for (int i = 0; i < 16; i++)
                acc += sm[k][i] * w[((t*16 + i)*5) + k];
        h1[(long)n*NQ_ + 192 + t] = acc;
    }
}

// ---------------- quantum layer (in-place on h1) ----------------
__global__ void k_quantum(float* __restrict__ h1, const float* __restrict__ q_rot,
                          const float* __restrict__ q_ent, int layer) {
    __shared__ float tq[NQ_];
    int n = blockIdx.x;
    const float* rot = q_rot + (long)layer*NQ_*3;
    const float* ent = q_ent + (long)layer*(NQ_-1);
    for (int q = threadIdx.x; q < NQ_; q += blockDim.x) {
        float hv = h1[(long)n*NQ_ + q];
        tq[q] = sinf(hv + rot[q*3]) + sinf(hv + rot[q*3+1]) + sinf(hv + rot[q*3+2]);
    }
    __syncthreads();
    for (int q = threadIdx.x; q < NQ_; q += blockDim.x) {
        float v;
        if (q == NQ_-1) v = 0.f;
        else {
            int qm = (q == 0) ? (NQ_-1) : (q-1);
            v = tq[q]*sinf(ent[q]) + tq[qm]*cosf(ent[q]);
        }
        h1[(long)n*NQ_ + q] = v;
    }
}

// ---------------- generic tiled SGEMM: C = A[M,K] @ B + bias (all f32) ----------------
// BT=false: B is [K,N] row-major. BT=true: B is [N,K] row-major.
// blockIdx.z batches with element strides sA/sB/sC. K multiple of 16, M multiple of 64.
template<bool BT, bool RELU>
__global__ __launch_bounds__(256) void k_sgemm(
    const float* __restrict__ A, const float* __restrict__ Bm, float* __restrict__ C,
    const float* __restrict__ bias, int M, int N, int K,
    int lda, int ldb, int ldc, long sA, long sB, long sC)
{
    __shared__ float As[16][65];
    __shared__ float Bs[16][65];
    const long aoff = (long)blockIdx.z * sA;
    const long boff = (long)blockIdx.z * sB;
    const long coff = (long)blockIdx.z * sC;
    int tile_m = blockIdx.y * 64, tile_n = blockIdx.x * 64;
    int t = threadIdx.x;
    int ty = t >> 4, tx = t & 15;
    float acc[4][4] = {};
    for (int k0 = 0; k0 < K; k0 += 16) {
        #pragma unroll
        for (int i = 0; i < 4; i++) {
            int idx = t + i*256;
            int m = idx >> 4, k = idx & 15;
            As[k][m] = A[aoff + (long)(tile_m + m)*lda + k0 + k];
        }
        #pragma unroll
        for (int i = 0; i < 4; i++) {
            int idx = t + i*256;
            int k, n;
            if (BT) { k = idx & 15; n = idx >> 4; } else { n = idx & 63; k = idx >> 6; }
            int gn = tile_n + n;
            float v = 0.f;
            if (gn < N)
                v = Bm[boff + (BT ? ((long)gn*ldb + k0 + k) : ((long)(k0 + k)*ldb + gn))];
            Bs[k][n] = v;
        }
        __syncthreads();
        #pragma unroll
        for (int k = 0; k < 16; k++) {
            float a[4], b[4];
            #pragma unroll
            for (int i = 0; i < 4; i++) a[i] = As[k][ty*4 + i];
            #pragma unroll
            for (int j = 0; j < 4; j++) b[j] = Bs[k][tx*4 + j];
            #pragma unroll
            for (int i = 0; i < 4; i++)
                #pragma unroll
                for (int j = 0; j < 4; j++)
                    acc[i][j] += a[i]*b[j];
        }
        __syncthreads();
    }
    #pragma unroll
    for (int i = 0; i < 4; i++) {
        int m = tile_m + ty*4 + i;
        if (m >= M) continue;
        #pragma unroll
        for (int j = 0; j < 4; j++) {
            int n = tile_n + tx*4 + j;
            if (n >= N) continue;
            float v = acc[i][j] + (bias ? bias[n] : 0.f);
            if (RELU) v = fmaxf(v, 0.f);
            C[coff + (long)m*ldc + n] = v;
        }
    }
}

// ---------------- fused row-wise attention ----------------
// one block per (b, head, q); faithful mask bug: keys with mask==1 -> -1e9
__global__ __launch_bounds__(256) void k_attn(
    const float* __restrict__ Q, const float* __restrict__ K,
    const float* __restrict__ Vv, const int* __restrict__ mask,
    float* __restrict__ ctx)
{
    __shared__ float qs[HD_];
    __shared__ float sc[S_];
    __shared__ float red[256];
    int blk = blockIdx.x;
    int q  = blk % S_;
    int hh = (blk / S_) % H_;
    int b  = blk / (S_*H_);
    int t = threadIdx.x;
    const long base = (long)b*S_*D_ + hh*HD_;
    if (t < HD_) qs[t] = Q[base + (long)q*D_ + t];
    __syncthreads();
    float vals[4];
    float mymax = -1e30f;
    #pragma unroll
    for (int kk = 0; kk < 4; kk++) {
        int k = kk*256 + t;
        const float* kr = K + base + (long)k*D_;
        float dot = 0.f;
        #pragma unroll
        for (int d = 0; d < HD_; d++) dot += qs[d]*kr[d];
        dot *= 0.125f;                      // 1/sqrt(64)
        if (mask[b*S_ + k] == 1) dot = -1e9f;
        vals[kk] = dot;
        mymax = fmaxf(mymax, dot);
    }
    red[t] = mymax; __syncthreads();
    for (int off = 128; off > 0; off >>= 1) {
        if (t < off) red[t] = fmaxf(red[t], red[t+off]);
        __syncthreads();
    }
    float mx = red[0]; __syncthreads();
    float mysum = 0.f;
    #pragma unroll
    for (int kk = 0; kk < 4; kk++) {
        float e = expf(vals[kk] - mx);
        sc[kk*256 + t] = e;
        mysum += e;
    }
    red[t] = mysum; __syncthreads();
    for (int off = 128; off > 0; off >>= 1) {
        if (t < off) red[t] += red[t+off];
        __syncthreads();
    }
    float inv = 1.f / red[0];
    __syncthreads();
    int d = t & 63, g = t >> 6;
    float part = 0.f;
    for (int k = g*256; k < (g+1)*256; k++)
        part += sc[k] * Vv[base + (long)k*D_ + d];
    red[t] = part;
    __syncthreads();
    if (t < 64) {
        float v = (red[t] + red[t+64] + red[t+128] + red[t+192]) * inv;
        ctx[(long)(b*S_ + q)*D_ + hh*HD_ + d] = v;
    }
}

// ---------------- residual add + LayerNorm ----------------
__global__ void k_addln(const float* __restrict__ a, const float* __restrict__ bvec,
                        const float* __restrict__ g, const float* __restrict__ be,
                        float* __restrict__ out) {
    __shared__ float row[D_];
    __shared__ float red[256];
    int n = blockIdx.x, t = threadIdx.x;
    float lsum = 0.f;
    for (int d = t; d < D_; d += 256) {
        float v = a[(long)n*D_ + d] + bvec[(long)n*D_ + d];
        row[d] = v; lsum += v;
    }
    red[t] = lsum; __syncthreads();
    for (int off = 128; off > 0; off >>= 1) {
        if (t < off) red[t] += red[t+off];
        __syncthreads();
    }
    float mean = red[0] / D_; __syncthreads();
    float lvar = 0.f;
    for (int d = t; d < D_; d += 256) { float v = row[d]-mean; lvar += v*v; }
    red[t] = lvar; __syncthreads();
    for (int off = 128; off > 0; off >>= 1) {
        if (t < off) red[t] += red[t+off];
        __syncthreads();
    }
    float rstd = rsqrtf(red[0]/D_ + 1e-5f);
    for (int d = t; d < D_; d += 256)
        out[(long)n*D_ + d] = (row[d]-mean)*rstd*g[d] + be[d];
}

// ---------------- mean-pool over sequence ----------------
__global__ void k_pool(const float* __restrict__ h, float* __restrict__ pooled) {
    int b = blockIdx.x / 3;
    int d = (blockIdx.x % 3)*256 + threadIdx.x;
    float s = 0.f;
    for (int ss = 0; ss < S_; ss++) s += h[(long)(b*S_ + ss)*D_ + d];
    pooled[b*D_ + d] = s * (1.f/S_);
}

// ---------------- task head (6 outputs, f32) ----------------
__global__ void k_task(const float* __restrict__ pooled, const float* __restrict__ tw,
                       const float* __restrict__ tb, float* __restrict__ out) {
    int i = threadIdx.x;
    if (i >= 6) return;
    int b = i/3, j = i%3;
    float acc = tb[j];
    for (int d = 0; d < D_; d++) acc += pooled[b*D_ + d]*tw[d*3 + j];
    out[(long)NTOK*V_ + i] = acc;
}

extern "C" void kernel_launch(void* const* d_in, const int* in_sizes, int n_in,
                              void* d_out, int out_size, void* d_ws, size_t ws_size,
                              hipStream_t stream) {
    const int*   x      = (const int*)d_in[0];
    const int*   amask  = (const int*)d_in[1];
    const float* adj    = (const float*)d_in[2];
    const float* emb    = (const float*)d_in[3];
    const float* inc1_w = (const float*)d_in[4];  const float* inc1_b = (const float*)d_in[5];
    const float* inc3a_w= (const float*)d_in[6];  const float* inc3a_b= (const float*)d_in[7];
    const float* inc3b_w= (const float*)d_in[8];  const float* inc3b_b= (const float*)d_in[9];
    const float* inc5a_w= (const float*)d_in[10]; const float* inc5a_b= (const float*)d_in[11];
    const float* inc5b_w= (const float*)d_in[12]; const float* inc5b_b= (const float*)d_in[13];
    const float* incp_w = (const float*)d_in[14]; const float* incp_b = (const float*)d_in[15];
    const float* q_rot  = (const float*)d_in[16]; const float* q_ent  = (const float*)d_in[17];
    const float* gnn_w1 = (const float*)d_in[18]; const float* gnn_b1 = (const float*)d_in[19];
    const float* gnn_w2 = (const float*)d_in[20]; const float* gnn_b2 = (const float*)d_in[21];
    const float* wq = (const float*)d_in[22]; const float* bq = (const float*)d_in[23];
    const float* wk = (const float*)d_in[24]; const float* bk = (const float*)d_in[25];
    const float* wv = (const float*)d_in[26]; const float* bv = (const float*)d_in[27];
    const float* wo = (const float*)d_in[28]; const float* bo = (const float*)d_in[29];
    const float* ff_w1 = (const float*)d_in[30]; const float* ff_b1 = (const float*)d_in[31];
    const float* ff_w2 = (const float*)d_in[32]; const float* ff_b2 = (const float*)d_in[33];
    const float* ln1_g = (const float*)d_in[34]; const float* ln1_b = (const float*)d_in[35];
    const float* ln2_g = (const float*)d_in[36]; const float* ln2_b = (const float*)d_in[37];
    const float* out_w = (const float*)d_in[38]; const float* out_b = (const float*)d_in[39];
    const float* task_w= (const float*)d_in[40]; const float* task_b= (const float*)d_in[41];

    // f32 scratch staged inside d_out (f32 out buffer = 65.5M floats = 262 MB;
    // all scratch is dead by the time the final vocab GEMM overwrites it).
    float* F = (float*)d_out;
    const long TB = (long)NTOK * D_;            // 1,572,864 f32
    float* h0  = F;            // embedding
    float* mp  = F + 1*TB;     // maxpool
    float* h1  = F + 2*TB;     // main hidden stream
    float* tq  = F + 3*TB;     // adj@h scratch, later K
    float* Qb  = F + 4*TB;
    float* Vb  = F + 5*TB;
    float* ctxb= F + 6*TB;
    float* ao  = F + 7*TB;     // attn_out, later FF out
    float* hln = F + 8*TB;     // after LN1
    float* ff1 = F + 9*TB;     // [2048,3072] = 4*TB
    float* t3  = F + 13*TB;
    float* t5  = t3 + (long)NTOK*96;
    float* gb  = t5 + (long)NTOK*16;
    float* agb = gb + (long)NTOK*384;

    float* hf     = (float*)d_ws;               // final hidden [2048,768]
    float* pooled = hf + TB;                    // [2,768]

    auto g2 = [](int N, int M, int Z) { return dim3((unsigned)((N+63)/64), (unsigned)((M+63)/64), (unsigned)Z); };

    // 1. embedding + maxpool
    k_embed<<<dim3(NTOK), dim3(256), 0, stream>>>(x, emb, h0);
    k_maxpool<<<dim3(NTOK), dim3(256), 0, stream>>>(h0, mp);

    // 2. zero h1 (cols 256..767 stay zero = pad to NQ)
    hipMemsetAsync(h1, 0, (size_t)TB*4, stream);

    // 3. inception 1x1 branches (weights are [O,D] -> BT=true)
    k_sgemm<true,false><<<g2(64, NTOK, 1), 256, 0, stream>>>(
        h0, inc1_w, h1, inc1_b, NTOK, 64, D_, D_, D_, NQ_, 0, 0, 0);
    k_sgemm<true,false><<<g2(96, NTOK, 1), 256, 0, stream>>>(
        h0, inc3a_w, t3, inc3a_b, NTOK, 96, D_, D_, D_, 96, 0, 0, 0);
    k_sgemm<true,false><<<g2(16, NTOK, 1), 256, 0, stream>>>(
        h0, inc5a_w, t5, inc5a_b, NTOK, 16, D_, D_, D_, 16, 0, 0, 0);
    k_sgemm<true,false><<<g2(32, NTOK, 1), 256, 0, stream>>>(
        mp, incp_w, h1 + 224, incp_b, NTOK, 32, D_, D_, D_, NQ_, 0, 0, 0);

    // 4. k3 / k5 convs
    k_conv3<<<dim3(NTOK), dim3(128), 0, stream>>>(t3, inc3b_w, inc3b_b, h1);
    k_conv5<<<dim3(NTOK), dim3(64), 0, stream>>>(t5, inc5b_w, inc5b_b, h1);

    // 5. quantum layers
    k_quantum<<<dim3(NTOK), dim3(256), 0, stream>>>(h1, q_rot, q_ent, 0);
    k_quantum<<<dim3(NTOK), dim3(256), 0, stream>>>(h1, q_rot, q_ent, 1);

    // 6. GNN
    k_sgemm<false,false><<<g2(NQ_, S_, B_), 256, 0, stream>>>(
        adj, h1, tq, nullptr, S_, NQ_, S_, S_, NQ_, NQ_,
        (long)S_*S_, (long)S_*NQ_, (long)S_*NQ_);
    k_sgemm<false,true><<<g2(384, NTOK, 1), 256, 0, stream>>>(
        tq, gnn_w1, gb, gnn_b1, NTOK, 384, D_, D_, 384, 384, 0, 0, 0);
    k_sgemm<false,false><<<g2(384, S_, B_), 256, 0, stream>>>(
        adj, gb, agb, nullptr, S_, 384, S_, S_, 384, 384,
        (long)S_*S_, (long)S_*384, (long)S_*384);
    k_sgemm<false,false><<<g2(D_, NTOK, 1), 256, 0, stream>>>(
        agb, gnn_w2, h1, gnn_b2, NTOK, D_, 384, 384, D_, D_, 0, 0, 0);

    // 7. attention
    k_sgemm<false,false><<<g2(D_, NTOK, 1), 256, 0, stream>>>(
        h1, wq, Qb, bq, NTOK, D_, D_, D_, D_, D_, 0, 0, 0);
    k_sgemm<false,false><<<g2(D_, NTOK, 1), 256, 0, stream>>>(
        h1, wk, tq, bk, NTOK, D_, D_, D_, D_, D_, 0, 0, 0);
    k_sgemm<false,false><<<g2(D_, NTOK, 1), 256, 0, stream>>>(
        h1, wv, Vb, bv, NTOK, D_, D_, D_, D_, D_, 0, 0, 0);
    k_attn<<<dim3(B_*H_*S_), dim3(256), 0, stream>>>(Qb, tq, Vb, amask, ctxb);
    k_sgemm<false,false><<<g2(D_, NTOK, 1), 256, 0, stream>>>(
        ctxb, wo, ao, bo, NTOK, D_, D_, D_, D_, D_, 0, 0, 0);
    k_addln<<<dim3(NTOK), dim3(256), 0, stream>>>(h1, ao, ln1_g, ln1_b, hln);

    // 8. FFN
    k_sgemm<false,true><<<g2(4*D_, NTOK, 1), 256, 0, stream>>>(
        hln, ff_w1, ff1, ff_b1, NTOK, 4*D_, D_, D_, 4*D_, 4*D_, 0, 0, 0);
    k_sgemm<false,false><<<g2(D_, NTOK, 1), 256, 0, stream>>>(
        ff1, ff_w2, ao, ff_b2, NTOK, D_, 4*D_, 4*D_, D_, D_, 0, 0, 0);
    k_addln<<<dim3(NTOK), dim3(256), 0, stream>>>(hln, ao, ln2_g, ln2_b, hf);

    // 9. heads: pool first, vocab GEMM overwrites all d_out scratch, task last
    k_pool<<<dim3(B_*3), dim3(256), 0, stream>>>(hf, pooled);
    k_sgemm<false,false><<<g2(V_, NTOK, 1), 256, 0, stream>>>(
        hf, out_w, (float*)d_out, out_b, NTOK, V_, D_, D_, V_, V_, 0, 0, 0);
    k_task<<<dim3(1), dim3(64), 0, stream>>>(pooled, task_w, task_b, (float*)d_out);
}

// Round 4
// 1400.321 us; speedup vs baseline: 4.1606x; 4.1606x over previous
//
#include <hip/hip_runtime.h>
#include <hip/hip_bf16.h>

#define B_ 2
#define S_ 1024
#define D_ 768
#define H_ 12
#define HD_ 64
#define V_ 32000
#define NQ_ 768
#define NTOK (B_*S_)

typedef __attribute__((ext_vector_type(8))) short short8;
typedef __attribute__((ext_vector_type(4))) float f32x4;

__device__ __forceinline__ short f2bf(float f) {
    union { float f; unsigned u; } v; v.f = f;
    unsigned r = (v.u + 0x7FFFu + ((v.u >> 16) & 1u)) >> 16;
    return (short)r;
}

// ---------------- embedding ----------------
__global__ void k_embed(const int* __restrict__ x, const float* __restrict__ emb,
                        float* __restrict__ h0) {
    int n = blockIdx.x;
    int row = x[n];
    for (int d = threadIdx.x; d < D_; d += blockDim.x)
        h0[(long)n*D_ + d] = emb[(long)row*D_ + d];
}

// ---------------- maxpool3 over sequence ----------------
__global__ void k_maxpool(const float* __restrict__ h0, float* __restrict__ mp) {
    int n = blockIdx.x; int s = n % S_;
    for (int d = threadIdx.x; d < D_; d += blockDim.x) {
        float m = h0[(long)n*D_ + d];
        if (s > 0)      m = fmaxf(m, h0[(long)(n-1)*D_ + d]);
        if (s < S_-1)   m = fmaxf(m, h0[(long)(n+1)*D_ + d]);
        mp[(long)n*D_ + d] = m;
    }
}

// ---------------- conv k=3 (96 -> 128), pad 1, writes h1 cols 64..191 ----------------
__global__ void k_conv3(const float* __restrict__ t3, const float* __restrict__ w,
                        const float* __restrict__ bias, float* __restrict__ h1) {
    __shared__ float sm[3][96];
    int n = blockIdx.x; int s = n % S_;
    int t = threadIdx.x;                   // 128 threads
    for (int idx = t; idx < 3*96; idx += 128) {
        int k = idx / 96, i = idx % 96;
        int ss = s + k - 1;
        sm[k][i] = (ss >= 0 && ss < S_) ? t3[(long)(n + k - 1)*96 + i] : 0.f;
    }
    __syncthreads();
    int o = t;
    float acc = bias[o];
    #pragma unroll
    for (int k = 0; k < 3; k++)
        for (int i = 0; i < 96; i++)
            acc += sm[k][i] * w[((o*96 + i)*3) + k];
    h1[(long)n*NQ_ + 64 + o] = acc;
}

// ---------------- conv k=5 (16 -> 32), pad 2, writes h1 cols 192..223 ----------------
__global__ void k_conv5(const float* __restrict__ t5, const float* __restrict__ w,
                        const float* __restrict__ bias, float* __restrict__ h1) {
    __shared__ float sm[5][16];
    int n = blockIdx.x; int s = n % S_;
    int t = threadIdx.x;                   // 64 threads
    for (int idx = t; idx < 5*16; idx += 64) {
        int k = idx / 16, i = idx % 16;
        int ss = s + k - 2;
        sm[k][i] = (ss >= 0 && ss < S_) ? t5[(long)(n + k - 2)*16 + i] : 0.f;
    }
    __syncthreads();
    if (t < 32) {
        float acc = bias[t];
        #pragma unroll
        for (int k = 0; k < 5; k++)
            for (int i = 0; i < 16; i++)
                acc += sm[k][i] * w[((t*16 + i)*5) + k];
        h1[(long)n*NQ_ + 192 + t] = acc;
    }
}

// ---------------- quantum layer (in-place on h1) ----------------
__global__ void k_quantum(float* __restrict__ h1, const float* __restrict__ q_rot,
                          const float* __restrict__ q_ent, int layer) {
    __shared__ float tq[NQ_];
    int n = blockIdx.x;
    const float* rot = q_rot + (long)layer*NQ_*3;
    const float* ent = q_ent + (long)layer*(NQ_-1);
    for (int q = threadIdx.x; q < NQ_; q += blockDim.x) {
        float hv = h1[(long)n*NQ_ + q];
        tq[q] = sinf(hv + rot[q*3]) + sinf(hv + rot[q*3+1]) + sinf(hv + rot[q*3+2]);
    }
    __syncthreads();
    for (int q = threadIdx.x; q < NQ_; q += blockDim.x) {
        float v;
        if (q == NQ_-1) v = 0.f;
        else {
            int qm = (q == 0) ? (NQ_-1) : (q-1);
            v = tq[q]*sinf(ent[q]) + tq[qm]*cosf(ent[q]);
        }
        h1[(long)n*NQ_ + q] = v;
    }
}

// ---------------- f32 tiled SGEMM (kept for small-N inception 1x1s) ----------------
template<bool BT, bool RELU>
__global__ __launch_bounds__(256) void k_sgemm(
    const float* __restrict__ A, const float* __restrict__ Bm, float* __restrict__ C,
    const float* __restrict__ bias, int M, int N, int K,
    int lda, int ldb, int ldc, long sA, long sB, long sC)
{
    __shared__ float As[16][65];
    __shared__ float Bs[16][65];
    const long aoff = (long)blockIdx.z * sA;
    const long boff = (long)blockIdx.z * sB;
    const long coff = (long)blockIdx.z * sC;
    int tile_m = blockIdx.y * 64, tile_n = blockIdx.x * 64;
    int t = threadIdx.x;
    int ty = t >> 4, tx = t & 15;
    float acc[4][4] = {};
    for (int k0 = 0; k0 < K; k0 += 16) {
        #pragma unroll
        for (int i = 0; i < 4; i++) {
            int idx = t + i*256;
            int m = idx >> 4, k = idx & 15;
            As[k][m] = A[aoff + (long)(tile_m + m)*lda + k0 + k];
        }
        #pragma unroll
        for (int i = 0; i < 4; i++) {
            int idx = t + i*256;
            int k, n;
            if (BT) { k = idx & 15; n = idx >> 4; } else { n = idx & 63; k = idx >> 6; }
            int gn = tile_n + n;
            float v = 0.f;
            if (gn < N)
                v = Bm[boff + (BT ? ((long)gn*ldb + k0 + k) : ((long)(k0 + k)*ldb + gn))];
            Bs[k][n] = v;
        }
        __syncthreads();
        #pragma unroll
        for (int k = 0; k < 16; k++) {
            float a[4], b[4];
            #pragma unroll
            for (int i = 0; i < 4; i++) a[i] = As[k][ty*4 + i];
            #pragma unroll
            for (int j = 0; j < 4; j++) b[j] = Bs[k][tx*4 + j];
            #pragma unroll
            for (int i = 0; i < 4; i++)
                #pragma unroll
                for (int j = 0; j < 4; j++)
                    acc[i][j] += a[i]*b[j];
        }
        __syncthreads();
    }
    #pragma unroll
    for (int i = 0; i < 4; i++) {
        int m = tile_m + ty*4 + i;
        if (m >= M) continue;
        #pragma unroll
        for (int j = 0; j < 4; j++) {
            int n = tile_n + tx*4 + j;
            if (n >= N) continue;
            float v = acc[i][j] + (bias ? bias[n] : 0.f);
            if (RELU) v = fmaxf(v, 0.f);
            C[coff + (long)m*ldc + n] = v;
        }
    }
}

// ---------------- bf16 MFMA GEMM: C = scale*(A@B) + bias ----------------
// f32 A,B in global; converted to bf16 in-register during staging.
// Tile 128x128, BK=32, 4 waves (2x2), each wave 4x4 frags of 16x16x32.
// BT: B is [N,K] row-major. HEADOUT: C written head-major [B,H,S,64].
// AHEAD: A read head-major [B,H,S,64] as logical [NTOK,768].
// Requirements: M % 128 == 0, K % 32 == 0. N guarded.
template<bool BT, bool RELU, bool HEADOUT, bool AHEAD>
__global__ __launch_bounds__(256) void k_mfma(
    const float* __restrict__ A, const float* __restrict__ Bm, float* __restrict__ C,
    const float* __restrict__ bias, float scale,
    int N, int K, int lda, int ldb, int ldc,
    long sA, long sB, long sC)
{
    __shared__ short lds[2][8192];   // per buf: A = [0,4096) shorts, B = [4096,8192)
    const int t = threadIdx.x;
    const int lane = t & 63;
    const int wave = t >> 6;
    const int wm = wave >> 1, wn = wave & 1;
    const int l15 = lane & 15, l4 = lane >> 4;
    const long aoff = (long)blockIdx.z * sA;
    const long boff = (long)blockIdx.z * sB;
    const long coff = (long)blockIdx.z * sC;
    const int tile_m = blockIdx.x * 128;   // x = M tiles (consecutive blocks reuse B panel in L2)
    const int tile_n = blockIdx.y * 128;

    const int arow = t >> 1, akh = t & 1;   // A staging: row 0..127, k-half (16 k each)
    const int bcol = t & 127, bkh = t >> 7; // B staging: col 0..127, k-half

    f32x4 areg[4];
    float breg[16];

    auto aload = [&](int k0) {
        int kst = k0 + akh*16;
        const float* ap;
        if (AHEAD) {
            int rowg = tile_m + arow;
            ap = A + ((long)((rowg >> 10)*H_ + (kst >> 6)))*(S_*HD_)
                   + (long)(rowg & (S_-1))*HD_ + (kst & (HD_-1));
        } else {
            ap = A + aoff + (long)(tile_m + arow)*lda + kst;
        }
        #pragma unroll
        for (int u = 0; u < 4; u++) areg[u] = *(const f32x4*)(ap + 4*u);
    };
    auto bload = [&](int k0) {
        int kst = k0 + bkh*16;
        int gn = tile_n + bcol;
        if (BT) {
            if (gn < N) {
                const float* bp = Bm + boff + (long)gn*ldb + kst;
                #pragma unroll
                for (int u = 0; u < 4; u++) {
                    f32x4 v = *(const f32x4*)(bp + 4*u);
                    breg[4*u+0] = v.x; breg[4*u+1] = v.y; breg[4*u+2] = v.z; breg[4*u+3] = v.w;
                }
            } else {
                #pragma unroll
                for (int j = 0; j < 16; j++) breg[j] = 0.f;
            }
        } else {
            #pragma unroll
            for (int j = 0; j < 16; j++)
                breg[j] = (gn < N) ? Bm[boff + (long)(kst + j)*ldb + gn] : 0.f;
        }
    };
    auto stage_write = [&](int buf) {
        short ta[16];
        #pragma unroll
        for (int u = 0; u < 4; u++) {
            ta[4*u+0] = f2bf(areg[u].x); ta[4*u+1] = f2bf(areg[u].y);
            ta[4*u+2] = f2bf(areg[u].z); ta[4*u+3] = f2bf(areg[u].w);
        }
        int g = arow >> 4, r = arow & 15;
        short* ab = &lds[buf][g*512 + (akh*2)*128 + r*8];
        *(short8*)(ab)       = *(const short8*)&ta[0];
        *(short8*)(ab + 128) = *(const short8*)&ta[8];
        short tb[16];
        #pragma unroll
        for (int j = 0; j < 16; j++) tb[j] = f2bf(breg[j]);
        int ng = bcol >> 4, c16 = bcol & 15;
        short* bb = &lds[buf][4096 + (bkh*2)*1024 + ng*128 + c16*8];
        *(short8*)(bb)        = *(const short8*)&tb[0];
        *(short8*)(bb + 1024) = *(const short8*)&tb[8];
    };

    f32x4 acc[4][4] = {};
    const int nk = K >> 5;

    aload(0); bload(0); stage_write(0);
    __syncthreads();
    int cur = 0;
    for (int ks = 0; ks < nk; ks++) {
        if (ks + 1 < nk) { aload((ks+1) << 5); bload((ks+1) << 5); }
        short8 af[4], bf[4];
        #pragma unroll
        for (int m = 0; m < 4; m++)
            af[m] = *(const short8*)&lds[cur][(wm*4 + m)*512 + l4*128 + l15*8];
        #pragma unroll
        for (int n = 0; n < 4; n++)
            bf[n] = *(const short8*)&lds[cur][4096 + l4*1024 + (wn*4 + n)*128 + l15*8];
        #pragma unroll
        for (int m = 0; m < 4; m++)
            #pragma unroll
            for (int n = 0; n < 4; n++)
                acc[m][n] = __builtin_amdgcn_mfma_f32_16x16x32_bf16(af[m], bf[n], acc[m][n], 0, 0, 0);
        if (ks + 1 < nk) stage_write(cur ^ 1);
        __syncthreads();
        cur ^= 1;
    }

    #pragma unroll
    for (int i = 0; i < 4; i++) {
        #pragma unroll
        for (int j = 0; j < 4; j++) {
            int col = tile_n + wn*64 + j*16 + l15;
            if (col >= N) continue;
            float bv = bias ? bias[col] : 0.f;
            #pragma unroll
            for (int r = 0; r < 4; r++) {
                int row = tile_m + wm*64 + i*16 + l4*4 + r;
                float v = acc[i][j][r] * scale + bv;
                if (RELU) v = fmaxf(v, 0.f);
                if (HEADOUT) {
                    int b = row >> 10, s = row & (S_-1);
                    int h = col >> 6, d = col & (HD_-1);
                    C[((long)(b*H_ + h)*S_ + s)*HD_ + d] = v;
                } else {
                    C[coff + (long)row*ldc + col] = v;
                }
            }
        }
    }
}

// ---------------- masked softmax over scores' rows ----------------
// scores: [B*H, S, S] f32 (already scaled by 1/8); mask bug: mask==1 -> -1e9
__global__ __launch_bounds__(256) void k_softmax(float* __restrict__ sc,
                                                 const int* __restrict__ mask) {
    __shared__ float red[256];
    long row = blockIdx.x;                 // z*S + q, z = b*H + h
    int b = (int)(row >> 10) / H_;
    float* r = sc + row * S_;
    const int* mrow = mask + b * S_;
    int t = threadIdx.x;
    float v[4]; float mx = -1e30f;
    #pragma unroll
    for (int kk = 0; kk < 4; kk++) {
        int k = kk*256 + t;
        float s = r[k];
        if (mrow[k] == 1) s = -1e9f;
        v[kk] = s; mx = fmaxf(mx, s);
    }
    red[t] = mx; __syncthreads();
    for (int off = 128; off > 0; off >>= 1) {
        if (t < off) red[t] = fmaxf(red[t], red[t+off]);
        __syncthreads();
    }
    mx = red[0]; __syncthreads();
    float sum = 0.f;
    #pragma unroll
    for (int kk = 0; kk < 4; kk++) { v[kk] = expf(v[kk] - mx); sum += v[kk]; }
    red[t] = sum; __syncthreads();
    for (int off = 128; off > 0; off >>= 1) {
        if (t < off) red[t] += red[t+off];
        __syncthreads();
    }
    float inv = 1.f / red[0];
    #pragma unroll
    for (int kk = 0; kk < 4; kk++) r[kk*256 + t] = v[kk] * inv;
}

// ---------------- residual add + LayerNorm ----------------
__global__ void k_addln(const float* __restrict__ a, const float* __restrict__ bvec,
                        const float* __restrict__ g, const float* __restrict__ be,
                        float* __restrict__ out) {
    __shared__ float row[D_];
    __shared__ float red[256];
    int n = blockIdx.x, t = threadIdx.x;
    float lsum = 0.f;
    for (int d = t; d < D_; d += 256) {
        float v = a[(long)n*D_ + d] + bvec[(long)n*D_ + d];
        row[d] = v; lsum += v;
    }
    red[t] = lsum; __syncthreads();
    for (int off = 128; off > 0; off >>= 1) {
        if (t < off) red[t] += red[t+off];
        __syncthreads();
    }
    float mean = red[0] / D_; __syncthreads();
    float lvar = 0.f;
    for (int d = t; d < D_; d += 256) { float v = row[d]-mean; lvar += v*v; }
    red[t] = lvar; __syncthreads();
    for (int off = 128; off > 0; off >>= 1) {
        if (t < off) red[t] += red[t+off];
        __syncthreads();
    }
    float rstd = rsqrtf(red[0]/D_ + 1e-5f);
    for (int d = t; d < D_; d += 256)
        out[(long)n*D_ + d] = (row[d]-mean)*rstd*g[d] + be[d];
}

// ---------------- mean-pool over sequence ----------------
__global__ void k_pool(const float* __restrict__ h, float* __restrict__ pooled) {
    int b = blockIdx.x / 3;
    int d = (blockIdx.x % 3)*256 + threadIdx.x;
    float s = 0.f;
    for (int ss = 0; ss < S_; ss++) s += h[(long)(b*S_ + ss)*D_ + d];
    pooled[b*D_ + d] = s * (1.f/S_);
}

// ---------------- task head (6 outputs, f32) ----------------
__global__ void k_task(const float* __restrict__ pooled, const float* __restrict__ tw,
                       const float* __restrict__ tb, float* __restrict__ out) {
    int i = threadIdx.x;
    if (i >= 6) return;
    int b = i/3, j = i%3;
    float acc = tb[j];
    for (int d = 0; d < D_; d++) acc += pooled[b*D_ + d]*tw[d*3 + j];
    out[(long)NTOK*V_ + i] = acc;
}

extern "C" void kernel_launch(void* const* d_in, const int* in_sizes, int n_in,
                              void* d_out, int out_size, void* d_ws, size_t ws_size,
                              hipStream_t stream) {
    const int*   x      = (const int*)d_in[0];
    const int*   amask  = (const int*)d_in[1];
    const float* adj    = (const float*)d_in[2];
    const float* emb    = (const float*)d_in[3];
    const float* inc1_w = (const float*)d_in[4];  const float* inc1_b = (const float*)d_in[5];
    const float* inc3a_w= (const float*)d_in[6];  const float* inc3a_b= (const float*)d_in[7];
    const float* inc3b_w= (const float*)d_in[8];  const float* inc3b_b= (const float*)d_in[9];
    const float* inc5a_w= (const float*)d_in[10]; const float* inc5a_b= (const float*)d_in[11];
    const float* inc5b_w= (const float*)d_in[12]; const float* inc5b_b= (const float*)d_in[13];
    const float* incp_w = (const float*)d_in[14]; const float* incp_b = (const float*)d_in[15];
    const float* q_rot  = (const float*)d_in[16]; const float* q_ent  = (const float*)d_in[17];
    const float* gnn_w1 = (const float*)d_in[18]; const float* gnn_b1 = (const float*)d_in[19];
    const float* gnn_w2 = (const float*)d_in[20]; const float* gnn_b2 = (const float*)d_in[21];
    const float* wq = (const float*)d_in[22]; const float* bq = (const float*)d_in[23];
    const float* wk = (const float*)d_in[24]; const float* bk = (const float*)d_in[25];
    const float* wv = (const float*)d_in[26]; const float* bv = (const float*)d_in[27];
    const float* wo = (const float*)d_in[28]; const float* bo = (const float*)d_in[29];
    const float* ff_w1 = (const float*)d_in[30]; const float* ff_b1 = (const float*)d_in[31];
    const float* ff_w2 = (const float*)d_in[32]; const float* ff_b2 = (const float*)d_in[33];
    const float* ln1_g = (const float*)d_in[34]; const float* ln1_b = (const float*)d_in[35];
    const float* ln2_g = (const float*)d_in[36]; const float* ln2_b = (const float*)d_in[37];
    const float* out_w = (const float*)d_in[38]; const float* out_b = (const float*)d_in[39];
    const float* task_w= (const float*)d_in[40]; const float* task_b= (const float*)d_in[41];

    // f32 scratch staged inside d_out (65.5M f32 = 262 MB; all dead before vocab GEMM).
    float* F = (float*)d_out;
    const long TB = (long)NTOK * D_;            // 1,572,864 f32
    float* h0  = F;            // embedding
    float* mp  = F + 1*TB;     // maxpool
    float* h1  = F + 2*TB;     // main hidden stream
    float* Kh  = F + 3*TB;     // adj@h scratch, later K' head-major [B,H,S,64]
    float* Qh  = F + 4*TB;     // Q' head-major
    float* Vh  = F + 5*TB;     // V' head-major
    float* ctxh= F + 6*TB;     // ctx' head-major
    float* ao  = F + 7*TB;     // attn_out, later FF out
    float* hln = F + 8*TB;     // after LN1
    float* ff1 = F + 9*TB;     // [2048,3072] = 4*TB
    float* t3  = F + 13*TB;
    float* t5  = t3 + (long)NTOK*96;
    float* gb  = t5 + (long)NTOK*16;
    float* agb = gb + (long)NTOK*384;
    float* scores = F + 16*TB; // [B*H, S, S] f32 = 16*TB, ends at 32*TB < 65.5M

    float* hf     = (float*)d_ws;               // final hidden [2048,768] (read during vocab GEMM)
    float* pooled = hf + TB;                    // [2,768]

    auto g2 = [](int N, int M, int Z) { return dim3((unsigned)((N+63)/64), (unsigned)((M+63)/64), (unsigned)Z); };
    auto gm = [](int M, int N, int Z) { return dim3((unsigned)(M/128), (unsigned)((N+127)/128), (unsigned)Z); };

    // 1. embedding + maxpool
    k_embed<<<dim3(NTOK), dim3(256), 0, stream>>>(x, emb, h0);
    k_maxpool<<<dim3(NTOK), dim3(256), 0, stream>>>(h0, mp);

    // 2. zero h1 (cols 256..767 stay zero = pad to NQ)
    hipMemsetAsync(h1, 0, (size_t)TB*4, stream);

    // 3. inception 1x1 branches (weights [O,D] -> BT, small N: f32 path)
    k_sgemm<true,false><<<g2(64, NTOK, 1), 256, 0, stream>>>(
        h0, inc1_w, h1, inc1_b, NTOK, 64, D_, D_, D_, NQ_, 0, 0, 0);
    k_sgemm<true,false><<<g2(96, NTOK, 1), 256, 0, stream>>>(
        h0, inc3a_w, t3, inc3a_b, NTOK, 96, D_, D_, D_, 96, 0, 0, 0);
    k_sgemm<true,false><<<g2(16, NTOK, 1), 256, 0, stream>>>(
        h0, inc5a_w, t5, inc5a_b, NTOK, 16, D_, D_, D_, 16, 0, 0, 0);
    k_sgemm<true,false><<<g2(32, NTOK, 1), 256, 0, stream>>>(
        mp, incp_w, h1 + 224, incp_b, NTOK, 32, D_, D_, D_, NQ_, 0, 0, 0);

    // 4. k3 / k5 convs
    k_conv3<<<dim3(NTOK), dim3(128), 0, stream>>>(t3, inc3b_w, inc3b_b, h1);
    k_conv5<<<dim3(NTOK), dim3(64), 0, stream>>>(t5, inc5b_w, inc5b_b, h1);

    // 5. quantum layers
    k_quantum<<<dim3(NTOK), dim3(256), 0, stream>>>(h1, q_rot, q_ent, 0);
    k_quantum<<<dim3(NTOK), dim3(256), 0, stream>>>(h1, q_rot, q_ent, 1);

    // 6. GNN (bf16 MFMA)
    k_mfma<false,false,false,false><<<gm(S_, NQ_, B_), 256, 0, stream>>>(
        adj, h1, Kh, nullptr, 1.f, NQ_, S_, S_, NQ_, NQ_,
        (long)S_*S_, (long)S_*NQ_, (long)S_*NQ_);
    k_mfma<false,true,false,false><<<gm(NTOK, 384, 1), 256, 0, stream>>>(
        Kh, gnn_w1, gb, gnn_b1, 1.f, 384, D_, D_, 384, 384, 0, 0, 0);
    k_mfma<false,false,false,false><<<gm(S_, 384, B_), 256, 0, stream>>>(
        adj, gb, agb, nullptr, 1.f, 384, S_, S_, 384, 384,
        (long)S_*S_, (long)S_*384, (long)S_*384);
    k_mfma<false,false,false,false><<<gm(NTOK, D_, 1), 256, 0, stream>>>(
        agb, gnn_w2, h1, gnn_b2, 1.f, D_, 384, 384, D_, D_, 0, 0, 0);

    // 7. attention: QKV (head-major out), QK^T (scaled), masked softmax, PV, WO
    k_mfma<false,false,true,false><<<gm(NTOK, D_, 1), 256, 0, stream>>>(
        h1, wq, Qh, bq, 1.f, D_, D_, D_, D_, 0, 0, 0, 0);
    k_mfma<false,false,true,false><<<gm(NTOK, D_, 1), 256, 0, stream>>>(
        h1, wk, Kh, bk, 1.f, D_, D_, D_, D_, 0, 0, 0, 0);
    k_mfma<false,false,true,false><<<gm(NTOK, D_, 1), 256, 0, stream>>>(
        h1, wv, Vh, bv, 1.f, D_, D_, D_, D_, 0, 0, 0, 0);
    k_mfma<true,false,false,false><<<gm(S_, S_, B_*H_), 256, 0, stream>>>(
        Qh, Kh, scores, nullptr, 0.125f, S_, HD_, HD_, HD_, S_,
        (long)S_*HD_, (long)S_*HD_, (long)S_*S_);
    k_softmax<<<dim3(B_*H_*S_), dim3(256), 0, stream>>>(scores, amask);
    k_mfma<false,false,false,false><<<gm(S_, HD_, B_*H_), 256, 0, stream>>>(
        scores, Vh, ctxh, nullptr, 1.f, HD_, S_, S_, HD_, HD_,
        (long)S_*S_, (long)S_*HD_, (long)S_*HD_);
    k_mfma<false,false,false,true><<<gm(NTOK, D_, 1), 256, 0, stream>>>(
        ctxh, wo, ao, bo, 1.f, D_, D_, 0, D_, D_, 0, 0, 0);
    k_addln<<<dim3(NTOK), dim3(256), 0, stream>>>(h1, ao, ln1_g, ln1_b, hln);

    // 8. FFN
    k_mfma<false,true,false,false><<<gm(NTOK, 4*D_, 1), 256, 0, stream>>>(
        hln, ff_w1, ff1, ff_b1, 1.f, 4*D_, D_, D_, 4*D_, 4*D_, 0, 0, 0);
    k_mfma<false,false,false,false><<<gm(NTOK, D_, 1), 256, 0, stream>>>(
        ff1, ff_w2, ao, ff_b2, 1.f, D_, 4*D_, 4*D_, D_, D_, 0, 0, 0);
    k_addln<<<dim3(NTOK), dim3(256), 0, stream>>>(hln, ao, ln2_g, ln2_b, hf);

    // 9. heads: pool first, vocab GEMM overwrites all d_out scratch, task last
    k_pool<<<dim3(B_*3), dim3(256), 0, stream>>>(hf, pooled);
    k_mfma<false,false,false,false><<<gm(NTOK, V_, 1), 256, 0, stream>>>(
        hf, out_w, (float*)d_out, out_b, 1.f, V_, D_, D_, V_, V_, 0, 0, 0);
    k_task<<<dim3(1), dim3(64), 0, stream>>>(pooled, task_w, task_b, (float*)d_out);
}

// Round 5
// 1335.602 us; speedup vs baseline: 4.3622x; 1.0485x over previous
//
#include <hip/hip_runtime.h>
#include <hip/hip_bf16.h>

#define B_ 2
#define S_ 1024
#define D_ 768
#define H_ 12
#define HD_ 64
#define V_ 32000
#define NQ_ 768
#define NTOK (B_*S_)

typedef __attribute__((ext_vector_type(8))) short short8;
typedef __attribute__((ext_vector_type(4))) float f32x4;

typedef const __attribute__((address_space(1))) void* as1vp;
typedef __attribute__((address_space(3))) void* as3vp;

__device__ __forceinline__ short f2bf(float f) {
    union { float f; unsigned u; } v; v.f = f;
    unsigned r = (v.u + 0x7FFFu + ((v.u >> 16) & 1u)) >> 16;
    return (short)r;
}
__device__ __forceinline__ float b2fs(short s) {
    union { unsigned u; float f; } v; v.u = ((unsigned)(unsigned short)s) << 16;
    return v.f;
}

// ---------------- embedding ----------------
__global__ void k_embed(const int* __restrict__ x, const float* __restrict__ emb,
                        float* __restrict__ h0) {
    int n = blockIdx.x;
    int row = x[n];
    for (int d = threadIdx.x; d < D_; d += blockDim.x)
        h0[(long)n*D_ + d] = emb[(long)row*D_ + d];
}

// ---------------- maxpool3 over sequence ----------------
__global__ void k_maxpool(const float* __restrict__ h0, float* __restrict__ mp) {
    int n = blockIdx.x; int s = n % S_;
    for (int d = threadIdx.x; d < D_; d += blockDim.x) {
        float m = h0[(long)n*D_ + d];
        if (s > 0)      m = fmaxf(m, h0[(long)(n-1)*D_ + d]);
        if (s < S_-1)   m = fmaxf(m, h0[(long)(n+1)*D_ + d]);
        mp[(long)n*D_ + d] = m;
    }
}

// ---------------- conv k=3 (96 -> 128), pad 1, writes h1 cols 64..191 ----------------
__global__ void k_conv3(const float* __restrict__ t3, const float* __restrict__ w,
                        const float* __restrict__ bias, float* __restrict__ h1) {
    __shared__ float sm[3][96];
    int n = blockIdx.x; int s = n % S_;
    int t = threadIdx.x;                   // 128 threads
    for (int idx = t; idx < 3*96; idx += 128) {
        int k = idx / 96, i = idx % 96;
        int ss = s + k - 1;
        sm[k][i] = (ss >= 0 && ss < S_) ? t3[(long)(n + k - 1)*96 + i] : 0.f;
    }
    __syncthreads();
    int o = t;
    float acc = bias[o];
    #pragma unroll
    for (int k = 0; k < 3; k++)
        for (int i = 0; i < 96; i++)
            acc += sm[k][i] * w[((o*96 + i)*3) + k];
    h1[(long)n*NQ_ + 64 + o] = acc;
}

// ---------------- conv k=5 (16 -> 32), pad 2, writes h1 cols 192..223 ----------------
__global__ void k_conv5(const float* __restrict__ t5, const float* __restrict__ w,
                        const float* __restrict__ bias, float* __restrict__ h1) {
    __shared__ float sm[5][16];
    int n = blockIdx.x; int s = n % S_;
    int t = threadIdx.x;                   // 64 threads
    for (int idx = t; idx < 5*16; idx += 64) {
        int k = idx / 16, i = idx % 16;
        int ss = s + k - 2;
        sm[k][i] = (ss >= 0 && ss < S_) ? t5[(long)(n + k - 2)*16 + i] : 0.f;
    }
    __syncthreads();
    if (t < 32) {
        float acc = bias[t];
        #pragma unroll
        for (int k = 0; k < 5; k++)
            for (int i = 0; i < 16; i++)
                acc += sm[k][i] * w[((t*16 + i)*5) + k];
        h1[(long)n*NQ_ + 192 + t] = acc;
    }
}

// ---------------- quantum layer (in-place on h1) ----------------
__global__ void k_quantum(float* __restrict__ h1, const float* __restrict__ q_rot,
                          const float* __restrict__ q_ent, int layer) {
    __shared__ float tq[NQ_];
    int n = blockIdx.x;
    const float* rot = q_rot + (long)layer*NQ_*3;
    const float* ent = q_ent + (long)layer*(NQ_-1);
    for (int q = threadIdx.x; q < NQ_; q += blockDim.x) {
        float hv = h1[(long)n*NQ_ + q];
        tq[q] = __sinf(hv + rot[q*3]) + __sinf(hv + rot[q*3+1]) + __sinf(hv + rot[q*3+2]);
    }
    __syncthreads();
    for (int q = threadIdx.x; q < NQ_; q += blockDim.x) {
        float v;
        if (q == NQ_-1) v = 0.f;
        else {
            int qm = (q == 0) ? (NQ_-1) : (q-1);
            v = tq[q]*__sinf(ent[q]) + tq[qm]*__cosf(ent[q]);
        }
        h1[(long)n*NQ_ + q] = v;
    }
}

// ---------------- f32 tiled SGEMM (inception 1x1 only) ----------------
template<bool BT, bool RELU>
__global__ __launch_bounds__(256) void k_sgemm(
    const float* __restrict__ A, const float* __restrict__ Bm, float* __restrict__ C,
    const float* __restrict__ bias, int M, int N, int K,
    int lda, int ldb, int ldc, long sA, long sB, long sC)
{
    __shared__ float As[16][65];
    __shared__ float Bs[16][65];
    const long aoff = (long)blockIdx.z * sA;
    const long boff = (long)blockIdx.z * sB;
    const long coff = (long)blockIdx.z * sC;
    int tile_m = blockIdx.y * 64, tile_n = blockIdx.x * 64;
    int t = threadIdx.x;
    int ty = t >> 4, tx = t & 15;
    float acc[4][4] = {};
    for (int k0 = 0; k0 < K; k0 += 16) {
        #pragma unroll
        for (int i = 0; i < 4; i++) {
            int idx = t + i*256;
            int m = idx >> 4, k = idx & 15;
            As[k][m] = A[aoff + (long)(tile_m + m)*lda + k0 + k];
        }
        #pragma unroll
        for (int i = 0; i < 4; i++) {
            int idx = t + i*256;
            int k, n;
            if (BT) { k = idx & 15; n = idx >> 4; } else { n = idx & 63; k = idx >> 6; }
            int gn = tile_n + n;
            float v = 0.f;
            if (gn < N)
                v = Bm[boff + (BT ? ((long)gn*ldb + k0 + k) : ((long)(k0 + k)*ldb + gn))];
            Bs[k][n] = v;
        }
        __syncthreads();
        #pragma unroll
        for (int k = 0; k < 16; k++) {
            float a[4], b[4];
            #pragma unroll
            for (int i = 0; i < 4; i++) a[i] = As[k][ty*4 + i];
            #pragma unroll
            for (int j = 0; j < 4; j++) b[j] = Bs[k][tx*4 + j];
            #pragma unroll
            for (int i = 0; i < 4; i++)
                #pragma unroll
                for (int j = 0; j < 4; j++)
                    acc[i][j] += a[i]*b[j];
        }
        __syncthreads();
    }
    #pragma unroll
    for (int i = 0; i < 4; i++) {
        int m = tile_m + ty*4 + i;
        if (m >= M) continue;
        #pragma unroll
        for (int j = 0; j < 4; j++) {
            int n = tile_n + tx*4 + j;
            if (n >= N) continue;
            float v = acc[i][j] + (bias ? bias[n] : 0.f);
            if (RELU) v = fmaxf(v, 0.f);
            C[coff + (long)m*ldc + n] = v;
        }
    }
}

// ---------------- f32->bf16 reg-staged MFMA GEMM (fallback vocab only) ----------------
template<bool BT, bool RELU, bool HEADOUT, bool AHEAD>
__global__ __launch_bounds__(256) void k_mfma(
    const float* __restrict__ A, const float* __restrict__ Bm, float* __restrict__ C,
    const float* __restrict__ bias, float scale,
    int N, int K, int lda, int ldb, int ldc,
    long sA, long sB, long sC)
{
    __shared__ short lds[2][8192];
    const int t = threadIdx.x;
    const int lane = t & 63;
    const int wave = t >> 6;
    const int wm = wave >> 1, wn = wave & 1;
    const int l15 = lane & 15, l4 = lane >> 4;
    const long aoff = (long)blockIdx.z * sA;
    const long boff = (long)blockIdx.z * sB;
    const long coff = (long)blockIdx.z * sC;
    const int tile_m = blockIdx.x * 128;
    const int tile_n = blockIdx.y * 128;
    const int arow = t >> 1, akh = t & 1;
    const int bcol = t & 127, bkh = t >> 7;
    f32x4 areg[4];
    float breg[16];
    auto aload = [&](int k0) {
        int kst = k0 + akh*16;
        const float* ap = A + aoff + (long)(tile_m + arow)*lda + kst;
        #pragma unroll
        for (int u = 0; u < 4; u++) areg[u] = *(const f32x4*)(ap + 4*u);
    };
    auto bload = [&](int k0) {
        int kst = k0 + bkh*16;
        int gn = tile_n + bcol;
        #pragma unroll
        for (int j = 0; j < 16; j++)
            breg[j] = (gn < N) ? Bm[boff + (long)(kst + j)*ldb + gn] : 0.f;
    };
    auto stage_write = [&](int buf) {
        short ta[16];
        #pragma unroll
        for (int u = 0; u < 4; u++) {
            ta[4*u+0] = f2bf(areg[u].x); ta[4*u+1] = f2bf(areg[u].y);
            ta[4*u+2] = f2bf(areg[u].z); ta[4*u+3] = f2bf(areg[u].w);
        }
        int g = arow >> 4, r = arow & 15;
        short* ab = &lds[buf][g*512 + (akh*2)*128 + r*8];
        *(short8*)(ab)       = *(const short8*)&ta[0];
        *(short8*)(ab + 128) = *(const short8*)&ta[8];
        short tb[16];
        #pragma unroll
        for (int j = 0; j < 16; j++) tb[j] = f2bf(breg[j]);
        int ng = bcol >> 4, c16 = bcol & 15;
        short* bb = &lds[buf][4096 + (bkh*2)*1024 + ng*128 + c16*8];
        *(short8*)(bb)        = *(const short8*)&tb[0];
        *(short8*)(bb + 1024) = *(const short8*)&tb[8];
    };
    f32x4 acc[4][4] = {};
    const int nk = K >> 5;
    aload(0); bload(0); stage_write(0);
    __syncthreads();
    int cur = 0;
    for (int ks = 0; ks < nk; ks++) {
        if (ks + 1 < nk) { aload((ks+1) << 5); bload((ks+1) << 5); }
        short8 af[4], bfv[4];
        #pragma unroll
        for (int m = 0; m < 4; m++)
            af[m] = *(const short8*)&lds[cur][(wm*4 + m)*512 + l4*128 + l15*8];
        #pragma unroll
        for (int n = 0; n < 4; n++)
            bfv[n] = *(const short8*)&lds[cur][4096 + l4*1024 + (wn*4 + n)*128 + l15*8];
        #pragma unroll
        for (int m = 0; m < 4; m++)
            #pragma unroll
            for (int n = 0; n < 4; n++)
                acc[m][n] = __builtin_amdgcn_mfma_f32_16x16x32_bf16(af[m], bfv[n], acc[m][n], 0, 0, 0);
        if (ks + 1 < nk) stage_write(cur ^ 1);
        __syncthreads();
        cur ^= 1;
    }
    #pragma unroll
    for (int i = 0; i < 4; i++) {
        #pragma unroll
        for (int j = 0; j < 4; j++) {
            int col = tile_n + wn*64 + j*16 + l15;
            if (col >= N) continue;
            float bv = bias ? bias[col] : 0.f;
            #pragma unroll
            for (int r = 0; r < 4; r++) {
                int row = tile_m + wm*64 + i*16 + l4*4 + r;
                float v = acc[i][j][r] * scale + bv;
                if (RELU) v = fmaxf(v, 0.f);
                C[coff + (long)row*ldc + col] = v;
            }
        }
    }
}

// ---------------- bf16 MFMA GEMM with global_load_lds staging ----------------
// A [M,K] bf16 row-major (or head-major if AMODE=1), B [N,K] bf16 row-major.
// Tile 128x128, BK=32, 4 waves 2x2. M mult of 128, K mult of 32, N guarded on store
// (OOB B-tile reads for N<128 land in adjacent allocated scratch, discarded).
// OMODE: 0=f32, 1=bf16, 2=dual(f32 C2 + bf16 Cv), 3=head-major bf16, 4=transposed-head bf16.
template<int AMODE, int OMODE, bool RELU>
__global__ __launch_bounds__(256) void k_bgemm(
    const short* __restrict__ A, const short* __restrict__ Bm,
    void* __restrict__ Cv, float* __restrict__ C2,
    const float* __restrict__ bias, float scale,
    int N, int K, int lda, int ldb, int ldc,
    long sA, long sB, long sC)
{
    __shared__ short lds[2][8192];   // per buf: A shorts [0,4096), B [4096,8192)
    const int t = threadIdx.x;
    const int lane = t & 63, wave = t >> 6;
    const int wm = wave >> 1, wn = wave & 1;
    const int l15 = lane & 15, l4 = lane >> 4;
    const int tile_m = blockIdx.x * 128, tile_n = blockIdx.y * 128;
    const long aoff = (long)blockIdx.z * sA;
    const long boff = (long)blockIdx.z * sB;
    const long coff = (long)blockIdx.z * sC;

    // staging: 512 16B-cells per tile; thread t owns cells t and t+256.
    // A cell c -> g=c>>6, kq=(c>>4)&3, r=c&15 : row=g*16+r, k=kq*8  (matches frag layout)
    // B cell c -> kq=c>>7, ng=(c>>4)&7, c16=c&15 : col=ng*16+c16, k=kq*8
    const int cA0 = t, cA1 = t + 256;
    const int arow0 = tile_m + ((cA0 >> 6) << 4) + (cA0 & 15);
    const int arow1 = tile_m + ((cA1 >> 6) << 4) + (cA1 & 15);
    const int akb0 = ((cA0 >> 4) & 3) * 8;
    const int akb1 = ((cA1 >> 4) & 3) * 8;
    const int bcol0 = tile_n + (((cA0 >> 4) & 7) << 4) + (cA0 & 15);
    const int bcol1 = tile_n + (((cA1 >> 4) & 7) << 4) + (cA1 & 15);
    const int bkb0 = (cA0 >> 7) * 8;
    const int bkb1 = (cA1 >> 7) * 8;
    const short* bp0 = Bm + boff + (long)bcol0*ldb + bkb0;
    const short* bp1 = Bm + boff + (long)bcol1*ldb + bkb1;
    const short* ap0 = nullptr; const short* ap1 = nullptr;
    long abase0 = 0, abase1 = 0;
    if (AMODE == 0) {
        ap0 = A + aoff + (long)arow0*lda + akb0;
        ap1 = A + aoff + (long)arow1*lda + akb1;
    } else {
        abase0 = ((long)((arow0 >> 10)*H_) * S_ + (arow0 & (S_-1))) * 64;
        abase1 = ((long)((arow1 >> 10)*H_) * S_ + (arow1 & (S_-1))) * 64;
    }
    const int wb = wave * 1024;   // wave-uniform byte offset within each 4KB chunk group

    auto stage = [&](int buf, int k0) {
        char* lb = (char*)&lds[buf][0];
        const short *a0, *a1;
        if (AMODE == 0) { a0 = ap0 + k0; a1 = ap1 + k0; }
        else {
            int ka0 = k0 + akb0, ka1 = k0 + akb1;
            a0 = A + abase0 + (long)(ka0 >> 6)*(S_*64) + (ka0 & 63);
            a1 = A + abase1 + (long)(ka1 >> 6)*(S_*64) + (ka1 & 63);
        }
        __builtin_amdgcn_global_load_lds((as1vp)a0,          (as3vp)(lb + wb),          16, 0, 0);
        __builtin_amdgcn_global_load_lds((as1vp)a1,          (as3vp)(lb + 4096 + wb),   16, 0, 0);
        __builtin_amdgcn_global_load_lds((as1vp)(bp0 + k0),  (as3vp)(lb + 8192 + wb),   16, 0, 0);
        __builtin_amdgcn_global_load_lds((as1vp)(bp1 + k0),  (as3vp)(lb + 12288 + wb),  16, 0, 0);
    };

    f32x4 acc[4][4] = {};
    const int nk = K >> 5;
    stage(0, 0);
    __syncthreads();
    int cur = 0;
    for (int ks = 0; ks < nk; ks++) {
        if (ks + 1 < nk) stage(cur ^ 1, (ks + 1) << 5);
        short8 af[4], bfv[4];
        const short* lb = &lds[cur][0];
        #pragma unroll
        for (int m = 0; m < 4; m++)
            af[m] = *(const short8*)(lb + (wm*4 + m)*512 + l4*128 + l15*8);
        #pragma unroll
        for (int n = 0; n < 4; n++)
            bfv[n] = *(const short8*)(lb + 4096 + l4*1024 + (wn*4 + n)*128 + l15*8);
        #pragma unroll
        for (int m = 0; m < 4; m++)
            #pragma unroll
            for (int n = 0; n < 4; n++)
                acc[m][n] = __builtin_amdgcn_mfma_f32_16x16x32_bf16(af[m], bfv[n], acc[m][n], 0, 0, 0);
        __syncthreads();
        cur ^= 1;
    }

    #pragma unroll
    for (int m = 0; m < 4; m++) {
        #pragma unroll
        for (int n = 0; n < 4; n++) {
            int col = tile_n + wn*64 + n*16 + l15;
            if (col >= N) continue;
            float bv = bias ? bias[col] : 0.f;
            #pragma unroll
            for (int r = 0; r < 4; r++) {
                int row = tile_m + wm*64 + m*16 + l4*4 + r;
                float v = acc[m][n][r] * scale + bv;
                if (RELU) v = fmaxf(v, 0.f);
                if (OMODE == 0) {
                    ((float*)Cv)[coff + (long)row*ldc + col] = v;
                } else if (OMODE == 1) {
                    ((short*)Cv)[coff + (long)row*ldc + col] = f2bf(v);
                } else if (OMODE == 2) {
                    C2[coff + (long)row*ldc + col] = v;
                    ((short*)Cv)[coff + (long)row*ldc + col] = f2bf(v);
                } else if (OMODE == 3) {
                    int b = row >> 10, s = row & (S_-1), h = col >> 6, d = col & 63;
                    ((short*)Cv)[(((long)(b*H_ + h))*S_ + s)*64 + d] = f2bf(v);
                } else {
                    int b = row >> 10, s = row & (S_-1), h = col >> 6, d = col & 63;
                    ((short*)Cv)[(((long)(b*H_ + h))*64 + d)*S_ + s] = f2bf(v);
                }
            }
        }
    }
}

// ---------------- f32 -> bf16 convert ----------------
__global__ void k_f2b(const float* __restrict__ in, short* __restrict__ out, long n) {
    long i = ((long)blockIdx.x*256 + threadIdx.x)*4;
    if (i >= n) return;
    f32x4 v = *(const f32x4*)(in + i);
    out[i+0] = f2bf(v.x); out[i+1] = f2bf(v.y); out[i+2] = f2bf(v.z); out[i+3] = f2bf(v.w);
}

// ---------------- f32 [R,C] -> bf16 [C,R] transpose-convert (batched) ----------------
__global__ void k_t2b(const float* __restrict__ in, short* __restrict__ out,
                      int R, int C, long sIn, long sOut) {
    __shared__ float tile[32][33];
    int bc = blockIdx.x * 32, br = blockIdx.y * 32;
    const float* ip = in + (long)blockIdx.z * sIn;
    short* op = out + (long)blockIdx.z * sOut;
    int tx = threadIdx.x & 31, ty = threadIdx.x >> 5;   // 256 threads
    #pragma unroll
    for (int i = 0; i < 32; i += 8)
        tile[ty + i][tx] = ip[(long)(br + ty + i)*C + bc + tx];
    __syncthreads();
    #pragma unroll
    for (int i = 0; i < 32; i += 8)
        op[(long)(bc + ty + i)*R + br + tx] = f2bf(tile[tx][ty + i]);
}

// ---------------- masked softmax: f32 scores -> bf16 P ----------------
__global__ __launch_bounds__(256) void k_softmax(const float* __restrict__ sc,
                                                 short* __restrict__ P,
                                                 const int* __restrict__ mask) {
    __shared__ float red[256];
    long row = blockIdx.x;                 // z*S + q, z = b*H + h
    int b = (int)(row >> 10) / H_;
    const float* r = sc + row * S_;
    short* pr = P + row * S_;
    const int* mrow = mask + b * S_;
    int t = threadIdx.x;
    float v[4]; float mx = -1e30f;
    #pragma unroll
    for (int kk = 0; kk < 4; kk++) {
        int k = kk*256 + t;
        float s = r[k];
        if (mrow[k] == 1) s = -1e9f;
        v[kk] = s; mx = fmaxf(mx, s);
    }
    red[t] = mx; __syncthreads();
    for (int off = 128; off > 0; off >>= 1) {
        if (t < off) red[t] = fmaxf(red[t], red[t+off]);
        __syncthreads();
    }
    mx = red[0]; __syncthreads();
    float sum = 0.f;
    #pragma unroll
    for (int kk = 0; kk < 4; kk++) { v[kk] = expf(v[kk] - mx); sum += v[kk]; }
    red[t] = sum; __syncthreads();
    for (int off = 128; off > 0; off >>= 1) {
        if (t < off) red[t] += red[t+off];
        __syncthreads();
    }
    float inv = 1.f / red[0];
    #pragma unroll
    for (int kk = 0; kk < 4; kk++) pr[kk*256 + t] = f2bf(v[kk] * inv);
}

// ---------------- residual add + LayerNorm (writes f32 + bf16) ----------------
__global__ void k_addln(const float* __restrict__ a, const float* __restrict__ bvec,
                        const float* __restrict__ g, const float* __restrict__ be,
                        float* __restrict__ outf, short* __restrict__ outb) {
    __shared__ float row[D_];
    __shared__ float red[256];
    int n = blockIdx.x, t = threadIdx.x;
    float lsum = 0.f;
    for (int d = t; d < D_; d += 256) {
        float v = a[(long)n*D_ + d] + bvec[(long)n*D_ + d];
        row[d] = v; lsum += v;
    }
    red[t] = lsum; __syncthreads();
    for (int off = 128; off > 0; off >>= 1) {
        if (t < off) red[t] += red[t+off];
        __syncthreads();
    }
    float mean = red[0] / D_; __syncthreads();
    float lvar = 0.f;
    for (int d = t; d < D_; d += 256) { float v = row[d]-mean; lvar += v*v; }
    red[t] = lvar; __syncthreads();
    for (int off = 128; off > 0; off >>= 1) {
        if (t < off) red[t] += red[t+off];
        __syncthreads();
    }
    float rstd = rsqrtf(red[0]/D_ + 1e-5f);
    for (int d = t; d < D_; d += 256) {
        float v = (row[d]-mean)*rstd*g[d] + be[d];
        outf[(long)n*D_ + d] = v;
        outb[(long)n*D_ + d] = f2bf(v);
    }
}

// ---------------- mean-pool over sequence (bf16 in) ----------------
__global__ void k_pool(const short* __restrict__ h, float* __restrict__ pooled) {
    int b = blockIdx.x / 3;
    int d = (blockIdx.x % 3)*256 + threadIdx.x;
    float s = 0.f;
    for (int ss = 0; ss < S_; ss++) s += b2fs(h[(long)(b*S_ + ss)*D_ + d]);
    pooled[b*D_ + d] = s * (1.f/S_);
}

// ---------------- task head (6 outputs, f32) ----------------
__global__ void k_task(const float* __restrict__ pooled, const float* __restrict__ tw,
                       const float* __restrict__ tb, float* __restrict__ out) {
    int i = threadIdx.x;
    if (i >= 6) return;
    int b = i/3, j = i%3;
    float acc = tb[j];
    for (int d = 0; d < D_; d++) acc += pooled[b*D_ + d]*tw[d*3 + j];
    out[(long)NTOK*V_ + i] = acc;
}

extern "C" void kernel_launch(void* const* d_in, const int* in_sizes, int n_in,
                              void* d_out, int out_size, void* d_ws, size_t ws_size,
                              hipStream_t stream) {
    const int*   x      = (const int*)d_in[0];
    const int*   amask  = (const int*)d_in[1];
    const float* adj    = (const float*)d_in[2];
    const float* emb    = (const float*)d_in[3];
    const float* inc1_w = (const float*)d_in[4];  const float* inc1_b = (const float*)d_in[5];
    const float* inc3a_w= (const float*)d_in[6];  const float* inc3a_b= (const float*)d_in[7];
    const float* inc3b_w= (const float*)d_in[8];  const float* inc3b_b= (const float*)d_in[9];
    const float* inc5a_w= (const float*)d_in[10]; const float* inc5a_b= (const float*)d_in[11];
    const float* inc5b_w= (const float*)d_in[12]; const float* inc5b_b= (const float*)d_in[13];
    const float* incp_w = (const float*)d_in[14]; const float* incp_b = (const float*)d_in[15];
    const float* q_rot  = (const float*)d_in[16]; const float* q_ent  = (const float*)d_in[17];
    const float* gnn_w1 = (const float*)d_in[18]; const float* gnn_b1 = (const float*)d_in[19];
    const float* gnn_w2 = (const float*)d_in[20]; const float* gnn_b2 = (const float*)d_in[21];
    const float* wq = (const float*)d_in[22]; const float* bq = (const float*)d_in[23];
    const float* wk = (const float*)d_in[24]; const float* bk = (const float*)d_in[25];
    const float* wv = (const float*)d_in[26]; const float* bv = (const float*)d_in[27];
    const float* wo = (const float*)d_in[28]; const float* bo = (const float*)d_in[29];
    const float* ff_w1 = (const float*)d_in[30]; const float* ff_b1 = (const float*)d_in[31];
    const float* ff_w2 = (const float*)d_in[32]; const float* ff_b2 = (const float*)d_in[33];
    const float* ln1_g = (const float*)d_in[34]; const float* ln1_b = (const float*)d_in[35];
    const float* ln2_g = (const float*)d_in[36]; const float* ln2_b = (const float*)d_in[37];
    const float* out_w = (const float*)d_in[38]; const float* out_b = (const float*)d_in[39];
    const float* task_w= (const float*)d_in[40]; const float* task_b= (const float*)d_in[41];

    // ---- d_out arena (f32 slots; no region overlaps; vocab GEMM writes [0,65.536M) last) ----
    float* F = (float*)d_out;
    float* h0   = F + 0L;
    float* mp   = F + 1572864L;
    float* h1f  = F + 3145728L;
    float* t3   = F + 4718592L;
    float* t5   = F + 4915200L;
    float* gbf  = F + 4947968L;
    short* gt   = (short*)(F + 5734400L);
    short* t2b  = (short*)(F + 6127616L);
    short* h1t  = (short*)(F + 6520832L);
    short* adjb = (short*)(F + 7307264L);
    short* t1b  = (short*)(F + 8355840L);
    short* wqt  = (short*)(F + 9142272L);
    short* wkt  = (short*)(F + 9437184L);
    short* wvt  = (short*)(F + 9732096L);
    short* wot  = (short*)(F + 10027008L);
    short* gw1t = (short*)(F + 10321920L);
    short* gw2t = (short*)(F + 10469376L);
    short* fw1t = (short*)(F + 10616832L);
    short* fw2t = (short*)(F + 11796480L);
    float* h2f  = F + 12976128L;
    short* h2b  = (short*)(F + 14548992L);
    short* Qh   = (short*)(F + 15335424L);
    short* Kh   = (short*)(F + 16121856L);
    short* Vt   = (short*)(F + 16908288L);
    short* ctxh = (short*)(F + 17694720L);
    float* ao   = F + 18481152L;
    float* hlnf = F + 20054016L;
    short* hlnb = (short*)(F + 21626880L);
    short* ff1b = (short*)(F + 22413312L);
    float* ao2  = F + 25559040L;
    float* scores = F + 27131904L;             // 25,165,824 slots
    short* Pb   = (short*)(F + 52297728L);     // ends 64,880,640 < 65,536,000

    // ---- d_ws: buffers read while d_out is being overwritten by the vocab GEMM ----
    char* W = (char*)d_ws;
    short* hfb    = (short*)(W + 0);            // 3,145,728 B
    float* hff    = (float*)(W + 3145728);      // 6,291,456 B
    float* pooled = (float*)(W + 9437184);      // 6,144 B
    short* owt    = (short*)(W + 9443328);      // 49,152,000 B
    const bool fast = ws_size >= (size_t)58595328;

    auto g2 = [](int N, int M, int Z) { return dim3((unsigned)((N+63)/64), (unsigned)((M+63)/64), (unsigned)Z); };
    auto gb = [](int M, int N, int Z) { return dim3((unsigned)(M/128), (unsigned)((N+127)/128), (unsigned)Z); };

    // 0. one-time converts/transposes (independent regions)
    k_t2b<<<dim3(24,24,1), 256, 0, stream>>>(wq, wqt, D_, D_, 0, 0);
    k_t2b<<<dim3(24,24,1), 256, 0, stream>>>(wk, wkt, D_, D_, 0, 0);
    k_t2b<<<dim3(24,24,1), 256, 0, stream>>>(wv, wvt, D_, D_, 0, 0);
    k_t2b<<<dim3(24,24,1), 256, 0, stream>>>(wo, wot, D_, D_, 0, 0);
    k_t2b<<<dim3(12,24,1), 256, 0, stream>>>(gnn_w1, gw1t, D_, 384, 0, 0);
    k_t2b<<<dim3(24,12,1), 256, 0, stream>>>(gnn_w2, gw2t, 384, D_, 0, 0);
    k_t2b<<<dim3(96,24,1), 256, 0, stream>>>(ff_w1, fw1t, D_, 4*D_, 0, 0);
    k_t2b<<<dim3(24,96,1), 256, 0, stream>>>(ff_w2, fw2t, 4*D_, D_, 0, 0);
    k_f2b<<<dim3(2048), 256, 0, stream>>>(adj, adjb, (long)B_*S_*S_);
    if (fast)
        k_t2b<<<dim3(1000,24,1), 256, 0, stream>>>(out_w, owt, D_, V_, 0, 0);

    // 1. embedding + maxpool
    k_embed<<<dim3(NTOK), dim3(256), 0, stream>>>(x, emb, h0);
    k_maxpool<<<dim3(NTOK), dim3(256), 0, stream>>>(h0, mp);

    // 2. zero h1 (cols 256..767 stay zero = pad to NQ)
    hipMemsetAsync(h1f, 0, (size_t)NTOK*NQ_*4, stream);

    // 3. inception 1x1 branches (f32, small N)
    k_sgemm<true,false><<<g2(64, NTOK, 1), 256, 0, stream>>>(
        h0, inc1_w, h1f, inc1_b, NTOK, 64, D_, D_, D_, NQ_, 0, 0, 0);
    k_sgemm<true,false><<<g2(96, NTOK, 1), 256, 0, stream>>>(
        h0, inc3a_w, t3, inc3a_b, NTOK, 96, D_, D_, D_, 96, 0, 0, 0);
    k_sgemm<true,false><<<g2(16, NTOK, 1), 256, 0, stream>>>(
        h0, inc5a_w, t5, inc5a_b, NTOK, 16, D_, D_, D_, 16, 0, 0, 0);
    k_sgemm<true,false><<<g2(32, NTOK, 1), 256, 0, stream>>>(
        mp, incp_w, h1f + 224, incp_b, NTOK, 32, D_, D_, D_, NQ_, 0, 0, 0);

    // 4. k3 / k5 convs
    k_conv3<<<dim3(NTOK), dim3(128), 0, stream>>>(t3, inc3b_w, inc3b_b, h1f);
    k_conv5<<<dim3(NTOK), dim3(64), 0, stream>>>(t5, inc5b_w, inc5b_b, h1f);

    // 5. quantum layers
    k_quantum<<<dim3(NTOK), dim3(256), 0, stream>>>(h1f, q_rot, q_ent, 0);
    k_quantum<<<dim3(NTOK), dim3(256), 0, stream>>>(h1f, q_rot, q_ent, 1);

    // 6. GNN
    k_t2b<<<dim3(24,32,2), 256, 0, stream>>>(h1f, h1t, S_, NQ_, (long)S_*NQ_, (long)S_*NQ_);
    k_bgemm<0,1,false><<<gb(S_, NQ_, B_), 256, 0, stream>>>(
        adjb, h1t, t1b, nullptr, nullptr, 1.f, NQ_, S_, S_, S_, NQ_,
        (long)S_*S_, (long)NQ_*S_, (long)S_*NQ_);
    k_bgemm<0,0,true><<<gb(NTOK, 384, 1), 256, 0, stream>>>(
        t1b, gw1t, gbf, nullptr, gnn_b1, 1.f, 384, D_, D_, D_, 384, 0, 0, 0);
    k_t2b<<<dim3(12,32,2), 256, 0, stream>>>(gbf, gt, S_, 384, (long)S_*384, (long)S_*384);
    k_bgemm<0,1,false><<<gb(S_, 384, B_), 256, 0, stream>>>(
        adjb, gt, t2b, nullptr, nullptr, 1.f, 384, S_, S_, S_, 384,
        (long)S_*S_, (long)384*S_, (long)S_*384);
    k_bgemm<0,2,false><<<gb(NTOK, D_, 1), 256, 0, stream>>>(
        t2b, gw2t, h2b, h2f, gnn_b2, 1.f, D_, 384, 384, 384, D_, 0, 0, 0);

    // 7. attention
    k_bgemm<0,3,false><<<gb(NTOK, D_, 1), 256, 0, stream>>>(
        h2b, wqt, Qh, nullptr, bq, 1.f, D_, D_, D_, D_, D_, 0, 0, 0);
    k_bgemm<0,3,false><<<gb(NTOK, D_, 1), 256, 0, stream>>>(
        h2b, wkt, Kh, nullptr, bk, 1.f, D_, D_, D_, D_, D_, 0, 0, 0);
    k_bgemm<0,4,false><<<gb(NTOK, D_, 1), 256, 0, stream>>>(
        h2b, wvt, Vt, nullptr, bv, 1.f, D_, D_, D_, D_, D_, 0, 0, 0);
    k_bgemm<0,0,false><<<gb(S_, S_, B_*H_), 256, 0, stream>>>(
        Qh, Kh, scores, nullptr, nullptr, 0.125f, S_, HD_, HD_, HD_, S_,
        (long)S_*HD_, (long)S_*HD_, (long)S_*S_);
    k_softmax<<<dim3(B_*H_*S_), dim3(256), 0, stream>>>(scores, Pb, amask);
    k_bgemm<0,1,false><<<gb(S_, HD_, B_*H_), 256, 0, stream>>>(
        Pb, Vt, ctxh, nullptr, nullptr, 1.f, HD_, S_, S_, S_, HD_,
        (long)S_*S_, (long)HD_*S_, (long)S_*HD_);
    k_bgemm<1,0,false><<<gb(NTOK, D_, 1), 256, 0, stream>>>(
        ctxh, wot, ao, nullptr, bo, 1.f, D_, D_, D_, D_, D_, 0, 0, 0);
    k_addln<<<dim3(NTOK), dim3(256), 0, stream>>>(h2f, ao, ln1_g, ln1_b, hlnf, hlnb);

    // 8. FFN
    k_bgemm<0,1,true><<<gb(NTOK, 4*D_, 1), 256, 0, stream>>>(
        hlnb, fw1t, ff1b, nullptr, ff_b1, 1.f, 4*D_, D_, D_, D_, 4*D_, 0, 0, 0);
    k_bgemm<0,0,false><<<gb(NTOK, D_, 1), 256, 0, stream>>>(
        ff1b, fw2t, ao2, nullptr, ff_b2, 1.f, D_, 4*D_, 4*D_, 4*D_, D_, 0, 0, 0);
    k_addln<<<dim3(NTOK), dim3(256), 0, stream>>>(hlnf, ao2, ln2_g, ln2_b, hff, hfb);

    // 9. heads
    k_pool<<<dim3(B_*3), dim3(256), 0, stream>>>(hfb, pooled);
    if (fast) {
        k_bgemm<0,0,false><<<gb(NTOK, V_, 1), 256, 0, stream>>>(
            hfb, owt, (float*)d_out, nullptr, out_b, 1.f, V_, D_, D_, D_, V_, 0, 0, 0);
    } else {
        k_mfma<false,false,false,false><<<gb(NTOK, V_, 1), 256, 0, stream>>>(
            hff, out_w, (float*)d_out, out_b, 1.f, V_, D_, D_, V_, V_, 0, 0, 0);
    }
    k_task<<<dim3(1), dim3(64), 0, stream>>>(pooled, task_w, task_b, (float*)d_out);
}

// Round 6
// 999.643 us; speedup vs baseline: 5.8283x; 1.3361x over previous
//
#include <hip/hip_runtime.h>
#include <hip/hip_bf16.h>

#define B_ 2
#define S_ 1024
#define D_ 768
#define H_ 12
#define HD_ 64
#define V_ 32000
#define NQ_ 768
#define NTOK (B_*S_)
#define QKVS 1572864L   // shorts per Q/K/V segment [B,H,S,64]

typedef __attribute__((ext_vector_type(8))) short short8;
typedef __attribute__((ext_vector_type(4))) float f32x4;

typedef const __attribute__((address_space(1))) void* as1vp;
typedef __attribute__((address_space(3))) void* as3vp;

__device__ __forceinline__ short f2bf(float f) {
    union { float f; unsigned u; } v; v.f = f;
    unsigned r = (v.u + 0x7FFFu + ((v.u >> 16) & 1u)) >> 16;
    return (short)r;
}
__device__ __forceinline__ float b2fs(short s) {
    union { unsigned u; float f; } v; v.u = ((unsigned)(unsigned short)s) << 16;
    return v.f;
}

// ---------------- embedding -> bf16 ----------------
__global__ void k_embed(const int* __restrict__ x, const float* __restrict__ emb,
                        short* __restrict__ h0b) {
    int n = blockIdx.x;
    int row = x[n];
    for (int d = threadIdx.x; d < D_; d += blockDim.x)
        h0b[(long)n*D_ + d] = f2bf(emb[(long)row*D_ + d]);
}

// ---------------- maxpool3 over sequence (bf16 in/out) ----------------
__global__ void k_maxpool(const short* __restrict__ h0b, short* __restrict__ mpb) {
    int n = blockIdx.x; int s = n % S_;
    for (int d = threadIdx.x; d < D_; d += blockDim.x) {
        float m = b2fs(h0b[(long)n*D_ + d]);
        if (s > 0)      m = fmaxf(m, b2fs(h0b[(long)(n-1)*D_ + d]));
        if (s < S_-1)   m = fmaxf(m, b2fs(h0b[(long)(n+1)*D_ + d]));
        mpb[(long)n*D_ + d] = f2bf(m);
    }
}

// ---------------- copy CO cols 0..63 into h1f cols 0..63 ----------------
__global__ void k_copy64(const float* __restrict__ CO, float* __restrict__ h1f) {
    int n = blockIdx.x;
    int t = threadIdx.x;   // 64
    h1f[(long)n*NQ_ + t] = CO[(long)n*176 + t];
}

// ---------------- conv k=3 (96 -> 128), pad 1, reads CO ld=176 off=64 ----------------
__global__ void k_conv3(const float* __restrict__ CO, const float* __restrict__ w,
                        const float* __restrict__ bias, float* __restrict__ h1) {
    __shared__ float sm[3][96];
    int n = blockIdx.x; int s = n % S_;
    int t = threadIdx.x;                   // 128 threads
    for (int idx = t; idx < 3*96; idx += 128) {
        int k = idx / 96, i = idx % 96;
        int ss = s + k - 1;
        sm[k][i] = (ss >= 0 && ss < S_) ? CO[(long)(n + k - 1)*176 + 64 + i] : 0.f;
    }
    __syncthreads();
    int o = t;
    float acc = bias[o];
    #pragma unroll
    for (int k = 0; k < 3; k++)
        for (int i = 0; i < 96; i++)
            acc += sm[k][i] * w[((o*96 + i)*3) + k];
    h1[(long)n*NQ_ + 64 + o] = acc;
}

// ---------------- conv k=5 (16 -> 32), pad 2, reads CO ld=176 off=160 ----------------
__global__ void k_conv5(const float* __restrict__ CO, const float* __restrict__ w,
                        const float* __restrict__ bias, float* __restrict__ h1) {
    __shared__ float sm[5][16];
    int n = blockIdx.x; int s = n % S_;
    int t = threadIdx.x;                   // 64 threads
    for (int idx = t; idx < 5*16; idx += 64) {
        int k = idx / 16, i = idx % 16;
        int ss = s + k - 2;
        sm[k][i] = (ss >= 0 && ss < S_) ? CO[(long)(n + k - 2)*176 + 160 + i] : 0.f;
    }
    __syncthreads();
    if (t < 32) {
        float acc = bias[t];
        #pragma unroll
        for (int k = 0; k < 5; k++)
            for (int i = 0; i < 16; i++)
                acc += sm[k][i] * w[((t*16 + i)*5) + k];
        h1[(long)n*NQ_ + 192 + t] = acc;
    }
}

// ---------------- quantum layer (in-place on h1) ----------------
__global__ void k_quantum(float* __restrict__ h1, const float* __restrict__ q_rot,
                          const float* __restrict__ q_ent, int layer) {
    __shared__ float tq[NQ_];
    int n = blockIdx.x;
    const float* rot = q_rot + (long)layer*NQ_*3;
    const float* ent = q_ent + (long)layer*(NQ_-1);
    for (int q = threadIdx.x; q < NQ_; q += blockDim.x) {
        float hv = h1[(long)n*NQ_ + q];
        tq[q] = __sinf(hv + rot[q*3]) + __sinf(hv + rot[q*3+1]) + __sinf(hv + rot[q*3+2]);
    }
    __syncthreads();
    for (int q = threadIdx.x; q < NQ_; q += blockDim.x) {
        float v;
        if (q == NQ_-1) v = 0.f;
        else {
            int qm = (q == 0) ? (NQ_-1) : (q-1);
            v = tq[q]*__sinf(ent[q]) + tq[qm]*__cosf(ent[q]);
        }
        h1[(long)n*NQ_ + q] = v;
    }
}

// ---------------- bf16 MFMA GEMM with global_load_lds + XCD-chunk swizzle ----------------
// A [M,K] bf16 row-major (AMODE=1: head-major [B,H,S,64] read as [NTOK,768]).
// B [N,K] bf16 row-major. Tile 128x128, BK=32, 4 waves 2x2.
// M mult of 128, K mult of 32; N guarded on store (B OOB reads need allocated slack).
// OMODE: 0=f32, 1=bf16, 2=dual(f32 C2 + bf16 Cv), 5=fused-QKV routing (Cv=Qh base).
template<int AMODE, int OMODE, bool RELU>
__global__ __launch_bounds__(256) void k_bgemm(
    const short* __restrict__ A, const short* __restrict__ Bm,
    void* __restrict__ Cv, float* __restrict__ C2,
    const float* __restrict__ bias, float scale,
    int N, int K, int lda, int ldb, int ldc,
    long sA, long sB, long sC)
{
    __shared__ short lds[2][8192];   // per buf: A shorts [0,4096), B [4096,8192)
    const int t = threadIdx.x;
    const int lane = t & 63, wave = t >> 6;
    const int wm = wave >> 1, wn = wave & 1;
    const int l15 = lane & 15, l4 = lane >> 4;

    // XCD-chunked bijective remap (T1, m204 form) for unbatched grids:
    // round-robin dispatch means lin%8 = XCD; give each XCD a contiguous
    // logical range so the 16 M-blocks sharing a B-panel co-reside in one L2.
    int bx = blockIdx.x, by = blockIdx.y;
    if (gridDim.z == 1) {
        int lin = by * gridDim.x + bx;
        int nwg = gridDim.x * gridDim.y;
        int xcd = lin & 7, pos = lin >> 3;
        int q = nwg >> 3, r = nwg & 7;
        int lin2 = (xcd < r ? xcd*(q+1) : r*(q+1) + (xcd-r)*q) + pos;
        bx = lin2 % gridDim.x;
        by = lin2 / gridDim.x;
    }
    const int tile_m = bx * 128, tile_n = by * 128;
    const long aoff = (long)blockIdx.z * sA;
    const long boff = (long)blockIdx.z * sB;
    const long coff = (long)blockIdx.z * sC;

    // staging: 512 16B-cells per operand tile; thread t owns cells t and t+256.
    // A cell c -> g=c>>6, kq=(c>>4)&3, r=c&15 : row=g*16+r, k=kq*8 (fragment-linear)
    // B cell c -> kq=c>>7, ng=(c>>4)&7, c16=c&15 : col=ng*16+c16, k=kq*8
    const int cA0 = t, cA1 = t + 256;
    const int arow0 = tile_m + ((cA0 >> 6) << 4) + (cA0 & 15);
    const int arow1 = tile_m + ((cA1 >> 6) << 4) + (cA1 & 15);
    const int akb0 = ((cA0 >> 4) & 3) * 8;
    const int akb1 = ((cA1 >> 4) & 3) * 8;
    const int bcol0 = tile_n + (((cA0 >> 4) & 7) << 4) + (cA0 & 15);
    const int bcol1 = tile_n + (((cA1 >> 4) & 7) << 4) + (cA1 & 15);
    const int bkb0 = (cA0 >> 7) * 8;
    const int bkb1 = (cA1 >> 7) * 8;
    const short* bp0 = Bm + boff + (long)bcol0*ldb + bkb0;
    const short* bp1 = Bm + boff + (long)bcol1*ldb + bkb1;
    const short* ap0 = nullptr; const short* ap1 = nullptr;
    long abase0 = 0, abase1 = 0;
    if (AMODE == 0) {
        ap0 = A + aoff + (long)arow0*lda + akb0;
        ap1 = A + aoff + (long)arow1*lda + akb1;
    } else {
        abase0 = ((long)((arow0 >> 10)*H_) * S_ + (arow0 & (S_-1))) * 64;
        abase1 = ((long)((arow1 >> 10)*H_) * S_ + (arow1 & (S_-1))) * 64;
    }
    const int wb = wave * 1024;

    auto stage = [&](int buf, int k0) {
        char* lb = (char*)&lds[buf][0];
        const short *a0, *a1;
        if (AMODE == 0) { a0 = ap0 + k0; a1 = ap1 + k0; }
        else {
            int ka0 = k0 + akb0, ka1 = k0 + akb1;
            a0 = A + abase0 + (long)(ka0 >> 6)*(S_*64) + (ka0 & 63);
            a1 = A + abase1 + (long)(ka1 >> 6)*(S_*64) + (ka1 & 63);
        }
        __builtin_amdgcn_global_load_lds((as1vp)a0,          (as3vp)(lb + wb),          16, 0, 0);
        __builtin_amdgcn_global_load_lds((as1vp)a1,          (as3vp)(lb + 4096 + wb),   16, 0, 0);
        __builtin_amdgcn_global_load_lds((as1vp)(bp0 + k0),  (as3vp)(lb + 8192 + wb),   16, 0, 0);
        __builtin_amdgcn_global_load_lds((as1vp)(bp1 + k0),  (as3vp)(lb + 12288 + wb),  16, 0, 0);
    };

    f32x4 acc[4][4] = {};
    const int nk = K >> 5;
    stage(0, 0);
    __syncthreads();
    int cur = 0;
    for (int ks = 0; ks < nk; ks++) {
        if (ks + 1 < nk) stage(cur ^ 1, (ks + 1) << 5);
        short8 af[4], bfv[4];
        const short* lb = &lds[cur][0];
        #pragma unroll
        for (int m = 0; m < 4; m++)
            af[m] = *(const short8*)(lb + (wm*4 + m)*512 + l4*128 + l15*8);
        #pragma unroll
        for (int n = 0; n < 4; n++)
            bfv[n] = *(const short8*)(lb + 4096 + l4*1024 + (wn*4 + n)*128 + l15*8);
        #pragma unroll
        for (int m = 0; m < 4; m++)
            #pragma unroll
            for (int n = 0; n < 4; n++)
                acc[m][n] = __builtin_amdgcn_mfma_f32_16x16x32_bf16(af[m], bfv[n], acc[m][n], 0, 0, 0);
        __syncthreads();
        cur ^= 1;
    }

    #pragma unroll
    for (int m = 0; m < 4; m++) {
        #pragma unroll
        for (int n = 0; n < 4; n++) {
            int col = tile_n + wn*64 + n*16 + l15;
            if (col >= N) continue;
            float bv = bias ? bias[col] : 0.f;
            #pragma unroll
            for (int r = 0; r < 4; r++) {
                int row = tile_m + wm*64 + m*16 + l4*4 + r;
                float v = acc[m][n][r] * scale + bv;
                if (RELU) v = fmaxf(v, 0.f);
                if (OMODE == 0) {
                    ((float*)Cv)[coff + (long)row*ldc + col] = v;
                } else if (OMODE == 1) {
                    ((short*)Cv)[coff + (long)row*ldc + col] = f2bf(v);
                } else if (OMODE == 2) {
                    C2[coff + (long)row*ldc + col] = v;
                    ((short*)Cv)[coff + (long)row*ldc + col] = f2bf(v);
                } else {   // OMODE 5: fused QKV routing
                    int seg = (col >= 1536) ? 2 : ((col >= 768) ? 1 : 0);
                    int c = col - seg*768;
                    int hh = c >> 6, dd = c & 63;
                    int b = row >> 10, s = row & (S_-1);
                    long hidx = (long)(b*H_ + hh);
                    short* base = (short*)Cv;
                    if (seg < 2) base[(long)seg*QKVS + (hidx*S_ + s)*64 + dd] = f2bf(v);
                    else         base[2L*QKVS + (hidx*64 + dd)*S_ + s] = f2bf(v);
                }
            }
        }
    }
}

// ---------------- f32 -> bf16 convert ----------------
__global__ void k_f2b(const float* __restrict__ in, short* __restrict__ out, long n) {
    long i = ((long)blockIdx.x*256 + threadIdx.x)*4;
    if (i >= n) return;
    f32x4 v = *(const f32x4*)(in + i);
    out[i+0] = f2bf(v.x); out[i+1] = f2bf(v.y); out[i+2] = f2bf(v.z); out[i+3] = f2bf(v.w);
}

// ---------------- f32 [R,C] -> bf16 [C,R] transpose-convert (batched) ----------------
__global__ void k_t2b(const float* __restrict__ in, short* __restrict__ out,
                      int R, int C, long sIn, long sOut) {
    __shared__ float tile[32][33];
    int bc = blockIdx.x * 32, br = blockIdx.y * 32;
    const float* ip = in + (long)blockIdx.z * sIn;
    short* op = out + (long)blockIdx.z * sOut;
    int tx = threadIdx.x & 31, ty = threadIdx.x >> 5;   // 256 threads
    #pragma unroll
    for (int i = 0; i < 32; i += 8)
        tile[ty + i][tx] = ip[(long)(br + ty + i)*C + bc + tx];
    __syncthreads();
    #pragma unroll
    for (int i = 0; i < 32; i += 8)
        op[(long)(bc + ty + i)*R + br + tx] = f2bf(tile[tx][ty + i]);
}

// ---------------- bias concat: qkv [2304] ----------------
__global__ void k_bqkv(const float* __restrict__ bq, const float* __restrict__ bk,
                       const float* __restrict__ bv, float* __restrict__ out) {
    int i = blockIdx.x*256 + threadIdx.x;
    if (i >= 2304) return;
    out[i] = (i < 768) ? bq[i] : (i < 1536 ? bk[i-768] : bv[i-1536]);
}

// ---------------- bias concat: inception [176] ----------------
__global__ void k_binc(const float* __restrict__ b1, const float* __restrict__ b3,
                       const float* __restrict__ b5, float* __restrict__ out) {
    int i = threadIdx.x;
    if (i >= 176) return;
    out[i] = (i < 64) ? b1[i] : (i < 160 ? b3[i-64] : b5[i-160]);
}

// ---------------- masked softmax: f32 scores -> bf16 P ----------------
__global__ __launch_bounds__(256) void k_softmax(const float* __restrict__ sc,
                                                 short* __restrict__ P,
                                                 const int* __restrict__ mask) {
    __shared__ float red[256];
    long row = blockIdx.x;                 // z*S + q, z = b*H + h
    int b = (int)(row >> 10) / H_;
    const float* r = sc + row * S_;
    short* pr = P + row * S_;
    const int* mrow = mask + b * S_;
    int t = threadIdx.x;
    float v[4]; float mx = -1e30f;
    #pragma unroll
    for (int kk = 0; kk < 4; kk++) {
        int k = kk*256 + t;
        float s = r[k];
        if (mrow[k] == 1) s = -1e9f;
        v[kk] = s; mx = fmaxf(mx, s);
    }
    red[t] = mx; __syncthreads();
    for (int off = 128; off > 0; off >>= 1) {
        if (t < off) red[t] = fmaxf(red[t], red[t+off]);
        __syncthreads();
    }
    mx = red[0]; __syncthreads();
    float sum = 0.f;
    #pragma unroll
    for (int kk = 0; kk < 4; kk++) { v[kk] = expf(v[kk] - mx); sum += v[kk]; }
    red[t] = sum; __syncthreads();
    for (int off = 128; off > 0; off >>= 1) {
        if (t < off) red[t] += red[t+off];
        __syncthreads();
    }
    float inv = 1.f / red[0];
    #pragma unroll
    for (int kk = 0; kk < 4; kk++) pr[kk*256 + t] = f2bf(v[kk] * inv);
}

// ---------------- residual add + LayerNorm (f32 out optional + bf16 out) ----------------
__global__ void k_addln(const float* __restrict__ a, const float* __restrict__ bvec,
                        const float* __restrict__ g, const float* __restrict__ be,
                        float* __restrict__ outf, short* __restrict__ outb) {
    __shared__ float row[D_];
    __shared__ float red[256];
    int n = blockIdx.x, t = threadIdx.x;
    float lsum = 0.f;
    for (int d = t; d < D_; d += 256) {
        float v = a[(long)n*D_ + d] + bvec[(long)n*D_ + d];
        row[d] = v; lsum += v;
    }
    red[t] = lsum; __syncthreads();
    for (int off = 128; off > 0; off >>= 1) {
        if (t < off) red[t] += red[t+off];
        __syncthreads();
    }
    float mean = red[0] / D_; __syncthreads();
    float lvar = 0.f;
    for (int d = t; d < D_; d += 256) { float v = row[d]-mean; lvar += v*v; }
    red[t] = lvar; __syncthreads();
    for (int off = 128; off > 0; off >>= 1) {
        if (t < off) red[t] += red[t+off];
        __syncthreads();
    }
    float rstd = rsqrtf(red[0]/D_ + 1e-5f);
    for (int d = t; d < D_; d += 256) {
        float v = (row[d]-mean)*rstd*g[d] + be[d];
        if (outf) outf[(long)n*D_ + d] = v;
        outb[(long)n*D_ + d] = f2bf(v);
    }
}

// ---------------- mean-pool over sequence (bf16 in) ----------------
__global__ void k_pool(const short* __restrict__ h, float* __restrict__ pooled) {
    int b = blockIdx.x / 3;
    int d = (blockIdx.x % 3)*256 + threadIdx.x;
    float s = 0.f;
    for (int ss = 0; ss < S_; ss++) s += b2fs(h[(long)(b*S_ + ss)*D_ + d]);
    pooled[b*D_ + d] = s * (1.f/S_);
}

// ---------------- task head (6 outputs, f32) ----------------
__global__ void k_task(const float* __restrict__ pooled, const float* __restrict__ tw,
                       const float* __restrict__ tb, float* __restrict__ out) {
    int i = threadIdx.x;
    if (i >= 6) return;
    int b = i/3, j = i%3;
    float acc = tb[j];
    for (int d = 0; d < D_; d++) acc += pooled[b*D_ + d]*tw[d*3 + j];
    out[(long)NTOK*V_ + i] = acc;
}

extern "C" void kernel_launch(void* const* d_in, const int* in_sizes, int n_in,
                              void* d_out, int out_size, void* d_ws, size_t ws_size,
                              hipStream_t stream) {
    const int*   x      = (const int*)d_in[0];
    const int*   amask  = (const int*)d_in[1];
    const float* adj    = (const float*)d_in[2];
    const float* emb    = (const float*)d_in[3];
    const float* inc1_w = (const float*)d_in[4];  const float* inc1_b = (const float*)d_in[5];
    const float* inc3a_w= (const float*)d_in[6];  const float* inc3a_b= (const float*)d_in[7];
    const float* inc3b_w= (const float*)d_in[8];  const float* inc3b_b= (const float*)d_in[9];
    const float* inc5a_w= (const float*)d_in[10]; const float* inc5a_b= (const float*)d_in[11];
    const float* inc5b_w= (const float*)d_in[12]; const float* inc5b_b= (const float*)d_in[13];
    const float* incp_w = (const float*)d_in[14]; const float* incp_b = (const float*)d_in[15];
    const float* q_rot  = (const float*)d_in[16]; const float* q_ent  = (const float*)d_in[17];
    const float* gnn_w1 = (const float*)d_in[18]; const float* gnn_b1 = (const float*)d_in[19];
    const float* gnn_w2 = (const float*)d_in[20]; const float* gnn_b2 = (const float*)d_in[21];
    const float* wq = (const float*)d_in[22]; const float* bq = (const float*)d_in[23];
    const float* wk = (const float*)d_in[24]; const float* bk = (const float*)d_in[25];
    const float* wv = (const float*)d_in[26]; const float* bv = (const float*)d_in[27];
    const float* wo = (const float*)d_in[28]; const float* bo = (const float*)d_in[29];
    const float* ff_w1 = (const float*)d_in[30]; const float* ff_b1 = (const float*)d_in[31];
    const float* ff_w2 = (const float*)d_in[32]; const float* ff_b2 = (const float*)d_in[33];
    const float* ln1_g = (const float*)d_in[34]; const float* ln1_b = (const float*)d_in[35];
    const float* ln2_g = (const float*)d_in[36]; const float* ln2_b = (const float*)d_in[37];
    const float* out_w = (const float*)d_in[38]; const float* out_b = (const float*)d_in[39];
    const float* task_w= (const float*)d_in[40]; const float* task_b= (const float*)d_in[41];

    // ---- d_out arena (f32 slot offsets; static, non-overlapping; total 63.69M < 65.536M;
    //      everything dead before the vocab GEMM overwrites [0, 65.536M)) ----
    float* F = (float*)d_out;
    short* wqkvt = (short*)(F + 0L);           //  884,736 slots  [2304x768] bf16
    short* wot   = (short*)(F + 884736L);      //  294,912
    short* gw1t  = (short*)(F + 1179648L);     //  147,456
    short* gw2t  = (short*)(F + 1327104L);     //  147,456
    short* fw1t  = (short*)(F + 1474560L);     // 1,179,648
    short* fw2t  = (short*)(F + 2654208L);     // 1,179,648
    short* wincat= (short*)(F + 3833856L);     //  116,736 ([176+128 pad]x768)
    short* wincp = (short*)(F + 3950592L);     //   61,440 ([32+128 pad]x768)
    float* binc  = F + 4012032L;               //      256
    float* bqkv  = F + 4012288L;               //    2,304
    short* adjb  = (short*)(F + 4014592L);     // 1,048,576
    short* h0b   = (short*)(F + 5063168L);     //  786,432
    short* mpb   = (short*)(F + 5849600L);     //  786,432
    float* CO    = F + 6636032L;               //  360,448  [2048x176] f32
    float* h1f   = F + 6996480L;               // 1,572,864
    short* h1t   = (short*)(F + 8569344L);     //  786,432
    short* t1b   = (short*)(F + 9355776L);     //  786,432
    float* gbf   = F + 10142208L;              //  786,432
    short* gt    = (short*)(F + 10928640L);    //  393,216
    short* t2bv  = (short*)(F + 11321856L);    //  393,216
    float* h2f   = F + 11715072L;              // 1,572,864
    short* h2b   = (short*)(F + 13287936L);    //  786,432
    short* Qh    = (short*)(F + 14074368L);    //  786,432 (Kh, Vt follow contiguously: OMODE5)
    short* Kh    = (short*)(F + 14860800L);    //  786,432
    short* Vt    = (short*)(F + 15647232L);    //  786,432 (+65,536 pad for PV B-OOB)
    short* ctxh  = (short*)(F + 16499200L);    //  786,432
    float* ao    = F + 17285632L;              // 1,572,864
    float* hlnf  = F + 18858496L;              // 1,572,864
    short* hlnb  = (short*)(F + 20431360L);    //  786,432
    short* ff1b  = (short*)(F + 21217792L);    // 3,145,728
    float* ao2   = F + 24363520L;              // 1,572,864
    float* scores= F + 25936384L;              // 25,165,824
    short* Pb    = (short*)(F + 51102208L);    // 12,582,912 -> ends 63,685,120

    // ---- d_ws (>= 58.6 MB proven in R5): buffers read during the vocab GEMM ----
    char* W = (char*)d_ws;
    short* hfb    = (short*)(W + 0);            // 3,145,728 B final hidden bf16
    float* pooled = (float*)(W + 3145728);      // 6,144 B
    short* owt    = (short*)(W + 3151872);      // 49,152,000 B  [32000x768] bf16

    auto gb = [](int M, int N, int Z) { return dim3((unsigned)(M/128), (unsigned)((N+127)/128), (unsigned)Z); };

    // 0. one-time converts/transposes
    k_t2b<<<dim3(24,24,1), 256, 0, stream>>>(wq, wqkvt,                 D_, D_, 0, 0);
    k_t2b<<<dim3(24,24,1), 256, 0, stream>>>(wk, wqkvt + 768*768,       D_, D_, 0, 0);
    k_t2b<<<dim3(24,24,1), 256, 0, stream>>>(wv, wqkvt + 2*768*768,     D_, D_, 0, 0);
    k_t2b<<<dim3(24,24,1), 256, 0, stream>>>(wo, wot, D_, D_, 0, 0);
    k_t2b<<<dim3(12,24,1), 256, 0, stream>>>(gnn_w1, gw1t, D_, 384, 0, 0);
    k_t2b<<<dim3(24,12,1), 256, 0, stream>>>(gnn_w2, gw2t, 384, D_, 0, 0);
    k_t2b<<<dim3(96,24,1), 256, 0, stream>>>(ff_w1, fw1t, D_, 4*D_, 0, 0);
    k_t2b<<<dim3(24,96,1), 256, 0, stream>>>(ff_w2, fw2t, 4*D_, D_, 0, 0);
    k_t2b<<<dim3(1000,24,1), 256, 0, stream>>>(out_w, owt, D_, V_, 0, 0);
    k_f2b<<<dim3(2048), 256, 0, stream>>>(adj, adjb, (long)B_*S_*S_);
    k_f2b<<<dim3(48), 256, 0, stream>>>(inc1_w,  wincat,           64*768);
    k_f2b<<<dim3(72), 256, 0, stream>>>(inc3a_w, wincat + 64*768,  96*768);
    k_f2b<<<dim3(12), 256, 0, stream>>>(inc5a_w, wincat + 160*768, 16*768);
    k_f2b<<<dim3(24), 256, 0, stream>>>(incp_w,  wincp,            32*768);
    k_binc<<<dim3(1), 256, 0, stream>>>(inc1_b, inc3a_b, inc5a_b, binc);
    k_bqkv<<<dim3(9), 256, 0, stream>>>(bq, bk, bv, bqkv);

    // 1. embedding + maxpool (bf16)
    k_embed<<<dim3(NTOK), dim3(256), 0, stream>>>(x, emb, h0b);
    k_maxpool<<<dim3(NTOK), dim3(256), 0, stream>>>(h0b, mpb);

    // 2. zero h1 (cols 256..767 stay zero = pad to NQ)
    hipMemsetAsync(h1f, 0, (size_t)NTOK*NQ_*4, stream);

    // 3. inception: fused 1x1 (inc1|inc3a|inc5a) + incp, all MFMA
    k_bgemm<0,0,false><<<gb(NTOK, 176, 1), 256, 0, stream>>>(
        h0b, wincat, CO, nullptr, binc, 1.f, 176, D_, D_, D_, 176, 0, 0, 0);
    k_bgemm<0,0,false><<<gb(NTOK, 32, 1), 256, 0, stream>>>(
        mpb, wincp, h1f + 224, nullptr, incp_b, 1.f, 32, D_, D_, D_, NQ_, 0, 0, 0);
    k_copy64<<<dim3(NTOK), dim3(64), 0, stream>>>(CO, h1f);
    k_conv3<<<dim3(NTOK), dim3(128), 0, stream>>>(CO, inc3b_w, inc3b_b, h1f);
    k_conv5<<<dim3(NTOK), dim3(64), 0, stream>>>(CO, inc5b_w, inc5b_b, h1f);

    // 4. quantum layers
    k_quantum<<<dim3(NTOK), dim3(256), 0, stream>>>(h1f, q_rot, q_ent, 0);
    k_quantum<<<dim3(NTOK), dim3(256), 0, stream>>>(h1f, q_rot, q_ent, 1);

    // 5. GNN
    k_t2b<<<dim3(24,32,2), 256, 0, stream>>>(h1f, h1t, S_, NQ_, (long)S_*NQ_, (long)S_*NQ_);
    k_bgemm<0,1,false><<<gb(S_, NQ_, B_), 256, 0, stream>>>(
        adjb, h1t, t1b, nullptr, nullptr, 1.f, NQ_, S_, S_, S_, NQ_,
        (long)S_*S_, (long)NQ_*S_, (long)S_*NQ_);
    k_bgemm<0,0,true><<<gb(NTOK, 384, 1), 256, 0, stream>>>(
        t1b, gw1t, gbf, nullptr, gnn_b1, 1.f, 384, D_, D_, D_, 384, 0, 0, 0);
    k_t2b<<<dim3(12,32,2), 256, 0, stream>>>(gbf, gt, S_, 384, (long)S_*384, (long)S_*384);
    k_bgemm<0,1,false><<<gb(S_, 384, B_), 256, 0, stream>>>(
        adjb, gt, t2bv, nullptr, nullptr, 1.f, 384, S_, S_, S_, 384,
        (long)S_*S_, (long)384*S_, (long)S_*384);
    k_bgemm<0,2,false><<<gb(NTOK, D_, 1), 256, 0, stream>>>(
        t2bv, gw2t, h2b, h2f, gnn_b2, 1.f, D_, 384, 384, 384, D_, 0, 0, 0);

    // 6. attention: fused QKV -> QK^T -> masked softmax -> PV -> WO -> add+LN
    k_bgemm<0,5,false><<<gb(NTOK, 3*D_, 1), 256, 0, stream>>>(
        h2b, wqkvt, Qh, nullptr, bqkv, 1.f, 3*D_, D_, D_, D_, 0, 0, 0, 0);
    k_bgemm<0,0,false><<<gb(S_, S_, B_*H_), 256, 0, stream>>>(
        Qh, Kh, scores, nullptr, nullptr, 0.125f, S_, HD_, HD_, HD_, S_,
        (long)S_*HD_, (long)S_*HD_, (long)S_*S_);
    k_softmax<<<dim3(B_*H_*S_), dim3(256), 0, stream>>>(scores, Pb, amask);
    k_bgemm<0,1,false><<<gb(S_, HD_, B_*H_), 256, 0, stream>>>(
        Pb, Vt, ctxh, nullptr, nullptr, 1.f, HD_, S_, S_, S_, HD_,
        (long)S_*S_, (long)HD_*S_, (long)S_*HD_);
    k_bgemm<1,0,false><<<gb(NTOK, D_, 1), 256, 0, stream>>>(
        ctxh, wot, ao, nullptr, bo, 1.f, D_, D_, D_, D_, D_, 0, 0, 0);
    k_addln<<<dim3(NTOK), dim3(256), 0, stream>>>(h2f, ao, ln1_g, ln1_b, hlnf, hlnb);

    // 7. FFN
    k_bgemm<0,1,true><<<gb(NTOK, 4*D_, 1), 256, 0, stream>>>(
        hlnb, fw1t, ff1b, nullptr, ff_b1, 1.f, 4*D_, D_, D_, D_, 4*D_, 0, 0, 0);
    k_bgemm<0,0,false><<<gb(NTOK, D_, 1), 256, 0, stream>>>(
        ff1b, fw2t, ao2, nullptr, ff_b2, 1.f, D_, 4*D_, 4*D_, 4*D_, D_, 0, 0, 0);
    k_addln<<<dim3(NTOK), dim3(256), 0, stream>>>(hlnf, ao2, ln2_g, ln2_b, nullptr, hfb);

    // 8. heads: pool, vocab GEMM (overwrites all d_out scratch), task
    k_pool<<<dim3(B_*3), dim3(256), 0, stream>>>(hfb, pooled);
    k_bgemm<0,0,false><<<gb(NTOK, V_, 1), 256, 0, stream>>>(
        hfb, owt, (float*)d_out, nullptr, out_b, 1.f, V_, D_, D_, D_, V_, 0, 0, 0);
    k_task<<<dim3(1), dim3(64), 0, stream>>>(pooled, task_w, task_b, (float*)d_out);
}

// Round 7
// 925.368 us; speedup vs baseline: 6.2961x; 1.0803x over previous
//
#include <hip/hip_runtime.h>
#include <hip/hip_bf16.h>

#define B_ 2
#define S_ 1024
#define D_ 768
#define H_ 12
#define HD_ 64
#define V_ 32000
#define NQ_ 768
#define NTOK (B_*S_)
#define QKVS 1572864L   // shorts per Q/K/V segment [B,H,S,64]

typedef __attribute__((ext_vector_type(8))) short short8;
typedef __attribute__((ext_vector_type(4))) float f32x4;

typedef const __attribute__((address_space(1))) void* as1vp;
typedef __attribute__((address_space(3))) void* as3vp;

__device__ __forceinline__ short f2bf(float f) {
    union { float f; unsigned u; } v; v.f = f;
    unsigned r = (v.u + 0x7FFFu + ((v.u >> 16) & 1u)) >> 16;
    return (short)r;
}
__device__ __forceinline__ float b2fs(short s) {
    union { unsigned u; float f; } v; v.u = ((unsigned)(unsigned short)s) << 16;
    return v.f;
}

// ---------------- embedding -> bf16 ----------------
__global__ void k_embed(const int* __restrict__ x, const float* __restrict__ emb,
                        short* __restrict__ h0b) {
    int n = blockIdx.x;
    int row = x[n];
    for (int d = threadIdx.x; d < D_; d += blockDim.x)
        h0b[(long)n*D_ + d] = f2bf(emb[(long)row*D_ + d]);
}

// ---------------- maxpool3 over sequence (bf16 in/out) ----------------
__global__ void k_maxpool(const short* __restrict__ h0b, short* __restrict__ mpb) {
    int n = blockIdx.x; int s = n % S_;
    for (int d = threadIdx.x; d < D_; d += blockDim.x) {
        float m = b2fs(h0b[(long)n*D_ + d]);
        if (s > 0)      m = fmaxf(m, b2fs(h0b[(long)(n-1)*D_ + d]));
        if (s < S_-1)   m = fmaxf(m, b2fs(h0b[(long)(n+1)*D_ + d]));
        mpb[(long)n*D_ + d] = f2bf(m);
    }
}

// ---------------- copy CO cols 0..63 into h1f cols 0..63 ----------------
__global__ void k_copy64(const float* __restrict__ CO, float* __restrict__ h1f) {
    int n = blockIdx.x;
    int t = threadIdx.x;   // 64
    h1f[(long)n*NQ_ + t] = CO[(long)n*176 + t];
}

// ---------------- conv k=3 (96 -> 128), pad 1, reads CO ld=176 off=64 ----------------
__global__ void k_conv3(const float* __restrict__ CO, const float* __restrict__ w,
                        const float* __restrict__ bias, float* __restrict__ h1) {
    __shared__ float sm[3][96];
    int n = blockIdx.x; int s = n % S_;
    int t = threadIdx.x;                   // 128 threads
    for (int idx = t; idx < 3*96; idx += 128) {
        int k = idx / 96, i = idx % 96;
        int ss = s + k - 1;
        sm[k][i] = (ss >= 0 && ss < S_) ? CO[(long)(n + k - 1)*176 + 64 + i] : 0.f;
    }
    __syncthreads();
    int o = t;
    float acc = bias[o];
    #pragma unroll
    for (int k = 0; k < 3; k++)
        for (int i = 0; i < 96; i++)
            acc += sm[k][i] * w[((o*96 + i)*3) + k];
    h1[(long)n*NQ_ + 64 + o] = acc;
}

// ---------------- conv k=5 (16 -> 32), pad 2, reads CO ld=176 off=160 ----------------
__global__ void k_conv5(const float* __restrict__ CO, const float* __restrict__ w,
                        const float* __restrict__ bias, float* __restrict__ h1) {
    __shared__ float sm[5][16];
    int n = blockIdx.x; int s = n % S_;
    int t = threadIdx.x;                   // 64 threads
    for (int idx = t; idx < 5*16; idx += 64) {
        int k = idx / 16, i = idx % 16;
        int ss = s + k - 2;
        sm[k][i] = (ss >= 0 && ss < S_) ? CO[(long)(n + k - 2)*176 + 160 + i] : 0.f;
    }
    __syncthreads();
    if (t < 32) {
        float acc = bias[t];
        #pragma unroll
        for (int k = 0; k < 5; k++)
            for (int i = 0; i < 16; i++)
                acc += sm[k][i] * w[((t*16 + i)*5) + k];
        h1[(long)n*NQ_ + 192 + t] = acc;
    }
}

// ---------------- quantum layer (in-place on h1) ----------------
__global__ void k_quantum(float* __restrict__ h1, const float* __restrict__ q_rot,
                          const float* __restrict__ q_ent, int layer) {
    __shared__ float tq[NQ_];
    int n = blockIdx.x;
    const float* rot = q_rot + (long)layer*NQ_*3;
    const float* ent = q_ent + (long)layer*(NQ_-1);
    for (int q = threadIdx.x; q < NQ_; q += blockDim.x) {
        float hv = h1[(long)n*NQ_ + q];
        tq[q] = __sinf(hv + rot[q*3]) + __sinf(hv + rot[q*3+1]) + __sinf(hv + rot[q*3+2]);
    }
    __syncthreads();
    for (int q = threadIdx.x; q < NQ_; q += blockDim.x) {
        float v;
        if (q == NQ_-1) v = 0.f;
        else {
            int qm = (q == 0) ? (NQ_-1) : (q-1);
            v = tq[q]*__sinf(ent[q]) + tq[qm]*__cosf(ent[q]);
        }
        h1[(long)n*NQ_ + q] = v;
    }
}

// ---------------- bf16 MFMA GEMM (128x128, 2-phase) ----------------
// A [M,K] bf16 row-major (AMODE=1: head-major [B,H,S,64] read as [NTOK,768]).
// B [N,K] bf16 row-major. Tile 128x128, BK=32, 4 waves 2x2.
// OMODE: 0=f32, 1=bf16, 2=dual, 5=fused-QKV routing (Cv=Qh base).
template<int AMODE, int OMODE, bool RELU>
__global__ __launch_bounds__(256) void k_bgemm(
    const short* __restrict__ A, const short* __restrict__ Bm,
    void* __restrict__ Cv, float* __restrict__ C2,
    const float* __restrict__ bias, float scale,
    int N, int K, int lda, int ldb, int ldc,
    long sA, long sB, long sC)
{
    __shared__ short lds[2][8192];   // per buf: A shorts [0,4096), B [4096,8192)
    const int t = threadIdx.x;
    const int lane = t & 63, wave = t >> 6;
    const int wm = wave >> 1, wn = wave & 1;
    const int l15 = lane & 15, l4 = lane >> 4;

    int bx = blockIdx.x, by = blockIdx.y;
    if (gridDim.z == 1) {
        int lin = by * gridDim.x + bx;
        int nwg = gridDim.x * gridDim.y;
        int xcd = lin & 7, pos = lin >> 3;
        int q = nwg >> 3, r = nwg & 7;
        int lin2 = (xcd < r ? xcd*(q+1) : r*(q+1) + (xcd-r)*q) + pos;
        bx = lin2 % gridDim.x;
        by = lin2 / gridDim.x;
    }
    const int tile_m = bx * 128, tile_n = by * 128;
    const long aoff = (long)blockIdx.z * sA;
    const long boff = (long)blockIdx.z * sB;
    const long coff = (long)blockIdx.z * sC;

    const int cA0 = t, cA1 = t + 256;
    const int arow0 = tile_m + ((cA0 >> 6) << 4) + (cA0 & 15);
    const int arow1 = tile_m + ((cA1 >> 6) << 4) + (cA1 & 15);
    const int akb0 = ((cA0 >> 4) & 3) * 8;
    const int akb1 = ((cA1 >> 4) & 3) * 8;
    const int bcol0 = tile_n + (((cA0 >> 4) & 7) << 4) + (cA0 & 15);
    const int bcol1 = tile_n + (((cA1 >> 4) & 7) << 4) + (cA1 & 15);
    const int bkb0 = (cA0 >> 7) * 8;
    const int bkb1 = (cA1 >> 7) * 8;
    const short* bp0 = Bm + boff + (long)bcol0*ldb + bkb0;
    const short* bp1 = Bm + boff + (long)bcol1*ldb + bkb1;
    const short* ap0 = nullptr; const short* ap1 = nullptr;
    long abase0 = 0, abase1 = 0;
    if (AMODE == 0) {
        ap0 = A + aoff + (long)arow0*lda + akb0;
        ap1 = A + aoff + (long)arow1*lda + akb1;
    } else {
        abase0 = ((long)((arow0 >> 10)*H_) * S_ + (arow0 & (S_-1))) * 64;
        abase1 = ((long)((arow1 >> 10)*H_) * S_ + (arow1 & (S_-1))) * 64;
    }
    const int wb = wave * 1024;

    auto stage = [&](int buf, int k0) {
        char* lb = (char*)&lds[buf][0];
        const short *a0, *a1;
        if (AMODE == 0) { a0 = ap0 + k0; a1 = ap1 + k0; }
        else {
            int ka0 = k0 + akb0, ka1 = k0 + akb1;
            a0 = A + abase0 + (long)(ka0 >> 6)*(S_*64) + (ka0 & 63);
            a1 = A + abase1 + (long)(ka1 >> 6)*(S_*64) + (ka1 & 63);
        }
        __builtin_amdgcn_global_load_lds((as1vp)a0,          (as3vp)(lb + wb),          16, 0, 0);
        __builtin_amdgcn_global_load_lds((as1vp)a1,          (as3vp)(lb + 4096 + wb),   16, 0, 0);
        __builtin_amdgcn_global_load_lds((as1vp)(bp0 + k0),  (as3vp)(lb + 8192 + wb),   16, 0, 0);
        __builtin_amdgcn_global_load_lds((as1vp)(bp1 + k0),  (as3vp)(lb + 12288 + wb),  16, 0, 0);
    };

    f32x4 acc[4][4] = {};
    const int nk = K >> 5;
    stage(0, 0);
    __syncthreads();
    int cur = 0;
    for (int ks = 0; ks < nk; ks++) {
        if (ks + 1 < nk) stage(cur ^ 1, (ks + 1) << 5);
        short8 af[4], bfv[4];
        const short* lb = &lds[cur][0];
        #pragma unroll
        for (int m = 0; m < 4; m++)
            af[m] = *(const short8*)(lb + (wm*4 + m)*512 + l4*128 + l15*8);
        #pragma unroll
        for (int n = 0; n < 4; n++)
            bfv[n] = *(const short8*)(lb + 4096 + l4*1024 + (wn*4 + n)*128 + l15*8);
        #pragma unroll
        for (int m = 0; m < 4; m++)
            #pragma unroll
            for (int n = 0; n < 4; n++)
                acc[m][n] = __builtin_amdgcn_mfma_f32_16x16x32_bf16(af[m], bfv[n], acc[m][n], 0, 0, 0);
        __syncthreads();
        cur ^= 1;
    }

    #pragma unroll
    for (int m = 0; m < 4; m++) {
        #pragma unroll
        for (int n = 0; n < 4; n++) {
            int col = tile_n + wn*64 + n*16 + l15;
            if (col >= N) continue;
            float bv = bias ? bias[col] : 0.f;
            #pragma unroll
            for (int r = 0; r < 4; r++) {
                int row = tile_m + wm*64 + m*16 + l4*4 + r;
                float v = acc[m][n][r] * scale + bv;
                if (RELU) v = fmaxf(v, 0.f);
                if (OMODE == 0) {
                    ((float*)Cv)[coff + (long)row*ldc + col] = v;
                } else if (OMODE == 1) {
                    ((short*)Cv)[coff + (long)row*ldc + col] = f2bf(v);
                } else if (OMODE == 2) {
                    C2[coff + (long)row*ldc + col] = v;
                    ((short*)Cv)[coff + (long)row*ldc + col] = f2bf(v);
                } else {   // OMODE 5: fused QKV routing
                    int seg = (col >= 1536) ? 2 : ((col >= 768) ? 1 : 0);
                    int c = col - seg*768;
                    int hh = c >> 6, dd = c & 63;
                    int b = row >> 10, s = row & (S_-1);
                    long hidx = (long)(b*H_ + hh);
                    short* base = (short*)Cv;
                    if (seg < 2) base[(long)seg*QKVS + (hidx*S_ + s)*64 + dd] = f2bf(v);
                    else         base[2L*QKVS + (hidx*64 + dd)*S_ + s] = f2bf(v);
                }
            }
        }
    }
}

// ---------------- 256x256 ring-4 counted-vmcnt MFMA GEMM (T3+T4+T5, vocab) ----------------
// A [M,K] bf16 row-major (M%256==0), B [N,K] bf16 row-major (N%256==0), K%64==0, K>=128.
// 512 threads = 8 waves (wm=wave>>2 in {0,1}, wn=wave&3). Per-wave C: 128x64.
// LDS: ring of 4 BK=32 sub-tile regions, each A 16KB + B 16KB -> 128 KiB dynamic.
// Per k-step: issue stage(s+2) -> vmcnt(8) -> barrier -> 12 ds_read_b128 -> 32 MFMA.
// Counted vmcnt keeps 2 k-steps of loads in flight across barriers (never drains to 0
// in steady state). Fragment-linear LDS layout: measured 0 bank conflicts (R5/R6).
__global__ __launch_bounds__(512, 2) void k_vgemm(
    const short* __restrict__ A, const short* __restrict__ Bm,
    float* __restrict__ C, const float* __restrict__ bias,
    int N, int K, int lda, int ldb, int ldc)
{
    extern __shared__ short lds[];   // 65536 shorts = 128 KiB
    const int t = threadIdx.x;
    const int lane = t & 63, wave = t >> 6;
    const int wm = wave >> 2, wn = wave & 3;
    const int l15 = lane & 15, l4 = lane >> 4;
    int bx = blockIdx.x, by = blockIdx.y;
    {   // XCD-chunked bijective swizzle: the 8 M-blocks sharing a B-panel -> one XCD/L2
        int lin = by * gridDim.x + bx;
        int nwg = gridDim.x * gridDim.y;
        int xcd = lin & 7, pos = lin >> 3;
        int q = nwg >> 3, r = nwg & 7;
        int lin2 = (xcd < r ? xcd*(q+1) : r*(q+1) + (xcd-r)*q) + pos;
        bx = lin2 % gridDim.x; by = lin2 / gridDim.x;
    }
    const int tile_m = bx * 256, tile_n = by * 256;

    // staging: per region 1024 chunks of 16B per operand; wave w owns chunks
    // [w*128, w*128+128) as two 64-lane issues. chunk c -> row=(c>>6)*16+(c&15),
    // k-offset=((c>>4)&3)*8  (fragment-linear: row-group*1024B + kq*256B + row*16B)
    const int c0 = wave*128 + lane;
    const int c1 = c0 + 64;
    const int ar0 = ((c0 >> 6) << 4) + (c0 & 15), ak0 = ((c0 >> 4) & 3) << 3;
    const int ar1 = ((c1 >> 6) << 4) + (c1 & 15), ak1 = ((c1 >> 4) & 3) << 3;
    const short* pa0 = A + (long)(tile_m + ar0)*lda + ak0;
    const short* pa1 = A + (long)(tile_m + ar1)*lda + ak1;
    const short* pb0 = Bm + (long)(tile_n + ar0)*ldb + ak0;
    const short* pb1 = Bm + (long)(tile_n + ar1)*ldb + ak1;
    char* lb = (char*)lds;
    const int wb0 = wave*2048, wb1 = wave*2048 + 1024;

    auto stage = [&](int reg, int s) {
        int k = s << 5;
        char* ab = lb + reg*32768;
        __builtin_amdgcn_global_load_lds((as1vp)(pa0 + k), (as3vp)(ab + wb0),         16, 0, 0);
        __builtin_amdgcn_global_load_lds((as1vp)(pa1 + k), (as3vp)(ab + wb1),         16, 0, 0);
        __builtin_amdgcn_global_load_lds((as1vp)(pb0 + k), (as3vp)(ab + 16384 + wb0), 16, 0, 0);
        __builtin_amdgcn_global_load_lds((as1vp)(pb1 + k), (as3vp)(ab + 16384 + wb1), 16, 0, 0);
    };

    f32x4 acc[8][4] = {};
    const int nks = K >> 5;
    stage(0, 0); stage(1, 1);
    const int ard = ((wm*8) << 10) + (l4 << 8) + l15*16;          // + fr<<10
    const int brd = 16384 + ((wn*4) << 10) + (l4 << 8) + l15*16;  // + fc<<10

    for (int s = 0; s < nks; s++) {
        const int reg = s & 3;
        if (s + 2 < nks) stage((s + 2) & 3, s + 2);   // region free: last read iter s-2
        if (s < nks - 2)       asm volatile("s_waitcnt vmcnt(8)" ::: "memory");
        else if (s == nks - 2) asm volatile("s_waitcnt vmcnt(4)" ::: "memory");
        else                   asm volatile("s_waitcnt vmcnt(0)" ::: "memory");
        __builtin_amdgcn_s_barrier();
        const char* rb = lb + reg*32768;
        short8 a[8], b[4];
        #pragma unroll
        for (int fr = 0; fr < 8; fr++) a[fr] = *(const short8*)(rb + ard + (fr << 10));
        #pragma unroll
        for (int fc = 0; fc < 4; fc++) b[fc] = *(const short8*)(rb + brd + (fc << 10));
        __builtin_amdgcn_s_setprio(1);
        #pragma unroll
        for (int fr = 0; fr < 8; fr++)
            #pragma unroll
            for (int fc = 0; fc < 4; fc++)
                acc[fr][fc] = __builtin_amdgcn_mfma_f32_16x16x32_bf16(a[fr], b[fc], acc[fr][fc], 0, 0, 0);
        __builtin_amdgcn_s_setprio(0);
    }

    #pragma unroll
    for (int fr = 0; fr < 8; fr++) {
        #pragma unroll
        for (int fc = 0; fc < 4; fc++) {
            int col = tile_n + wn*64 + fc*16 + l15;
            float bv = bias ? bias[col] : 0.f;
            #pragma unroll
            for (int rr = 0; rr < 4; rr++) {
                int row = tile_m + wm*128 + fr*16 + l4*4 + rr;
                C[(long)row*ldc + col] = acc[fr][fc][rr] + bv;
            }
        }
    }
}

// ---------------- f32 -> bf16 convert ----------------
__global__ void k_f2b(const float* __restrict__ in, short* __restrict__ out, long n) {
    long i = ((long)blockIdx.x*256 + threadIdx.x)*4;
    if (i >= n) return;
    f32x4 v = *(const f32x4*)(in + i);
    out[i+0] = f2bf(v.x); out[i+1] = f2bf(v.y); out[i+2] = f2bf(v.z); out[i+3] = f2bf(v.w);
}

// ---------------- f32 [R,C] -> bf16 [C,R] transpose-convert (batched) ----------------
__global__ void k_t2b(const float* __restrict__ in, short* __restrict__ out,
                      int R, int C, long sIn, long sOut) {
    __shared__ float tile[32][33];
    int bc = blockIdx.x * 32, br = blockIdx.y * 32;
    const float* ip = in + (long)blockIdx.z * sIn;
    short* op = out + (long)blockIdx.z * sOut;
    int tx = threadIdx.x & 31, ty = threadIdx.x >> 5;   // 256 threads
    #pragma unroll
    for (int i = 0; i < 32; i += 8)
        tile[ty + i][tx] = ip[(long)(br + ty + i)*C + bc + tx];
    __syncthreads();
    #pragma unroll
    for (int i = 0; i < 32; i += 8)
        op[(long)(bc + ty + i)*R + br + tx] = f2bf(tile[tx][ty + i]);
}

// ---------------- bias concat: qkv [2304] ----------------
__global__ void k_bqkv(const float* __restrict__ bq, const float* __restrict__ bk,
                       const float* __restrict__ bv, float* __restrict__ out) {
    int i = blockIdx.x*256 + threadIdx.x;
    if (i >= 2304) return;
    out[i] = (i < 768) ? bq[i] : (i < 1536 ? bk[i-768] : bv[i-1536]);
}

// ---------------- bias concat: inception [176] ----------------
__global__ void k_binc(const float* __restrict__ b1, const float* __restrict__ b3,
                       const float* __restrict__ b5, float* __restrict__ out) {
    int i = threadIdx.x;
    if (i >= 176) return;
    out[i] = (i < 64) ? b1[i] : (i < 160 ? b3[i-64] : b5[i-160]);
}

// ---------------- masked softmax: bf16 scores -> bf16 P ----------------
__global__ __launch_bounds__(256) void k_softmax(const short* __restrict__ sc,
                                                 short* __restrict__ P,
                                                 const int* __restrict__ mask) {
    __shared__ float red[256];
    long row = blockIdx.x;                 // z*S + q, z = b*H + h
    int b = (int)(row >> 10) / H_;
    const short* r = sc + row * S_;
    short* pr = P + row * S_;
    const int* mrow = mask + b * S_;
    int t = threadIdx.x;
    float v[4]; float mx = -1e30f;
    #pragma unroll
    for (int kk = 0; kk < 4; kk++) {
        int k = kk*256 + t;
        float s = b2fs(r[k]);
        if (mrow[k] == 1) s = -1e9f;
        v[kk] = s; mx = fmaxf(mx, s);
    }
    red[t] = mx; __syncthreads();
    for (int off = 128; off > 0; off >>= 1) {
        if (t < off) red[t] = fmaxf(red[t], red[t+off]);
        __syncthreads();
    }
    mx = red[0]; __syncthreads();
    float sum = 0.f;
    #pragma unroll
    for (int kk = 0; kk < 4; kk++) { v[kk] = expf(v[kk] - mx); sum += v[kk]; }
    red[t] = sum; __syncthreads();
    for (int off = 128; off > 0; off >>= 1) {
        if (t < off) red[t] += red[t+off];
        __syncthreads();
    }
    float inv = 1.f / red[0];
    #pragma unroll
    for (int kk = 0; kk < 4; kk++) pr[kk*256 + t] = f2bf(v[kk] * inv);
}

// ---------------- residual add + LayerNorm (f32 out optional + bf16 out) ----------------
__global__ void k_addln(const float* __restrict__ a, const float* __restrict__ bvec,
                        const float* __restrict__ g, const float* __restrict__ be,
                        float* __restrict__ outf, short* __restrict__ outb) {
    __shared__ float row[D_];
    __shared__ float red[256];
    int n = blockIdx.x, t = threadIdx.x;
    float lsum = 0.f;
    for (int d = t; d < D_; d += 256) {
        float v = a[(long)n*D_ + d] + bvec[(long)n*D_ + d];
        row[d] = v; lsum += v;
    }
    red[t] = lsum; __syncthreads();
    for (int off = 128; off > 0; off >>= 1) {
        if (t < off) red[t] += red[t+off];
        __syncthreads();
    }
    float mean = red[0] / D_; __syncthreads();
    float lvar = 0.f;
    for (int d = t; d < D_; d += 256) { float v = row[d]-mean; lvar += v*v; }
    red[t] = lvar; __syncthreads();
    for (int off = 128; off > 0; off >>= 1) {
        if (t < off) red[t] += red[t+off];
        __syncthreads();
    }
    float rstd = rsqrtf(red[0]/D_ + 1e-5f);
    for (int d = t; d < D_; d += 256) {
        float v = (row[d]-mean)*rstd*g[d] + be[d];
        if (outf) outf[(long)n*D_ + d] = v;
        outb[(long)n*D_ + d] = f2bf(v);
    }
}

// ---------------- mean-pool over sequence (bf16 in) ----------------
__global__ void k_pool(const short* __restrict__ h, float* __restrict__ pooled) {
    int b = blockIdx.x / 3;
    int d = (blockIdx.x % 3)*256 + threadIdx.x;
    float s = 0.f;
    for (int ss = 0; ss < S_; ss++) s += b2fs(h[(long)(b*S_ + ss)*D_ + d]);
    pooled[b*D_ + d] = s * (1.f/S_);
}

// ---------------- task head (6 outputs, f32) ----------------
__global__ void k_task(const float* __restrict__ pooled, const float* __restrict__ tw,
                       const float* __restrict__ tb, float* __restrict__ out) {
    int i = threadIdx.x;
    if (i >= 6) return;
    int b = i/3, j = i%3;
    float acc = tb[j];
    for (int d = 0; d < D_; d++) acc += pooled[b*D_ + d]*tw[d*3 + j];
    out[(long)NTOK*V_ + i] = acc;
}

extern "C" void kernel_launch(void* const* d_in, const int* in_sizes, int n_in,
                              void* d_out, int out_size, void* d_ws, size_t ws_size,
                              hipStream_t stream) {
    const int*   x      = (const int*)d_in[0];
    const int*   amask  = (const int*)d_in[1];
    const float* adj    = (const float*)d_in[2];
    const float* emb    = (const float*)d_in[3];
    const float* inc1_w = (const float*)d_in[4];  const float* inc1_b = (const float*)d_in[5];
    const float* inc3a_w= (const float*)d_in[6];  const float* inc3a_b= (const float*)d_in[7];
    const float* inc3b_w= (const float*)d_in[8];  const float* inc3b_b= (const float*)d_in[9];
    const float* inc5a_w= (const float*)d_in[10]; const float* inc5a_b= (const float*)d_in[11];
    const float* inc5b_w= (const float*)d_in[12]; const float* inc5b_b= (const float*)d_in[13];
    const float* incp_w = (const float*)d_in[14]; const float* incp_b = (const float*)d_in[15];
    const float* q_rot  = (const float*)d_in[16]; const float* q_ent  = (const float*)d_in[17];
    const float* gnn_w1 = (const float*)d_in[18]; const float* gnn_b1 = (const float*)d_in[19];
    const float* gnn_w2 = (const float*)d_in[20]; const float* gnn_b2 = (const float*)d_in[21];
    const float* wq = (const float*)d_in[22]; const float* bq = (const float*)d_in[23];
    const float* wk = (const float*)d_in[24]; const float* bk = (const float*)d_in[25];
    const float* wv = (const float*)d_in[26]; const float* bv = (const float*)d_in[27];
    const float* wo = (const float*)d_in[28]; const float* bo = (const float*)d_in[29];
    const float* ff_w1 = (const float*)d_in[30]; const float* ff_b1 = (const float*)d_in[31];
    const float* ff_w2 = (const float*)d_in[32]; const float* ff_b2 = (const float*)d_in[33];
    const float* ln1_g = (const float*)d_in[34]; const float* ln1_b = (const float*)d_in[35];
    const float* ln2_g = (const float*)d_in[36]; const float* ln2_b = (const float*)d_in[37];
    const float* out_w = (const float*)d_in[38]; const float* out_b = (const float*)d_in[39];
    const float* task_w= (const float*)d_in[40]; const float* task_b= (const float*)d_in[41];

    // ---- d_out arena (f32 slot offsets; non-overlapping; dead before vocab GEMM) ----
    float* F = (float*)d_out;
    short* wqkvt = (short*)(F + 0L);           //  884,736 slots
    short* wot   = (short*)(F + 884736L);
    short* gw1t  = (short*)(F + 1179648L);
    short* gw2t  = (short*)(F + 1327104L);
    short* fw1t  = (short*)(F + 1474560L);
    short* fw2t  = (short*)(F + 2654208L);
    short* wincat= (short*)(F + 3833856L);
    short* wincp = (short*)(F + 3950592L);
    float* binc  = F + 4012032L;
    float* bqkv  = F + 4012288L;
    short* adjb  = (short*)(F + 4014592L);
    short* h0b   = (short*)(F + 5063168L);
    short* mpb   = (short*)(F + 5849600L);
    float* CO    = F + 6636032L;
    float* h1f   = F + 6996480L;
    short* h1t   = (short*)(F + 8569344L);
    short* t1b   = (short*)(F + 9355776L);
    float* gbf   = F + 10142208L;
    short* gt    = (short*)(F + 10928640L);
    short* t2bv  = (short*)(F + 11321856L);
    float* h2f   = F + 11715072L;
    short* h2b   = (short*)(F + 13287936L);
    short* Qh    = (short*)(F + 14074368L);    // Kh, Vt contiguous (OMODE5)
    short* Kh    = (short*)(F + 14860800L);
    short* Vt    = (short*)(F + 15647232L);    // +pad for PV B-OOB
    short* ctxh  = (short*)(F + 16499200L);
    float* ao    = F + 17285632L;
    float* hlnf  = F + 18858496L;
    short* hlnb  = (short*)(F + 20431360L);
    short* ff1b  = (short*)(F + 21217792L);
    float* ao2   = F + 24363520L;
    short* scob  = (short*)(F + 25936384L);    // bf16 scores [B*H,S,S]
    short* Pb    = (short*)(F + 51102208L);

    // ---- d_ws (>= 58.6 MB proven): buffers read during the vocab GEMM ----
    char* W = (char*)d_ws;
    short* hfb    = (short*)(W + 0);
    float* pooled = (float*)(W + 3145728);
    short* owt    = (short*)(W + 3151872);     // [32000x768] bf16

    auto gb = [](int M, int N, int Z) { return dim3((unsigned)(M/128), (unsigned)((N+127)/128), (unsigned)Z); };

    // allow 128 KiB dynamic LDS for k_vgemm (no-op if already permitted)
    hipFuncSetAttribute((const void*)k_vgemm, hipFuncAttributeMaxDynamicSharedMemorySize, 131072);

    // 0. one-time converts/transposes
    k_t2b<<<dim3(24,24,1), 256, 0, stream>>>(wq, wqkvt,             D_, D_, 0, 0);
    k_t2b<<<dim3(24,24,1), 256, 0, stream>>>(wk, wqkvt + 768*768,   D_, D_, 0, 0);
    k_t2b<<<dim3(24,24,1), 256, 0, stream>>>(wv, wqkvt + 2*768*768, D_, D_, 0, 0);
    k_t2b<<<dim3(24,24,1), 256, 0, stream>>>(wo, wot, D_, D_, 0, 0);
    k_t2b<<<dim3(12,24,1), 256, 0, stream>>>(gnn_w1, gw1t, D_, 384, 0, 0);
    k_t2b<<<dim3(24,12,1), 256, 0, stream>>>(gnn_w2, gw2t, 384, D_, 0, 0);
    k_t2b<<<dim3(96,24,1), 256, 0, stream>>>(ff_w1, fw1t, D_, 4*D_, 0, 0);
    k_t2b<<<dim3(24,96,1), 256, 0, stream>>>(ff_w2, fw2t, 4*D_, D_, 0, 0);
    k_t2b<<<dim3(1000,24,1), 256, 0, stream>>>(out_w, owt, D_, V_, 0, 0);
    k_f2b<<<dim3(2048), 256, 0, stream>>>(adj, adjb, (long)B_*S_*S_);
    k_f2b<<<dim3(48), 256, 0, stream>>>(inc1_w,  wincat,           64*768);
    k_f2b<<<dim3(72), 256, 0, stream>>>(inc3a_w, wincat + 64*768,  96*768);
    k_f2b<<<dim3(12), 256, 0, stream>>>(inc5a_w, wincat + 160*768, 16*768);
    k_f2b<<<dim3(24), 256, 0, stream>>>(incp_w,  wincp,            32*768);
    k_binc<<<dim3(1), 256, 0, stream>>>(inc1_b, inc3a_b, inc5a_b, binc);
    k_bqkv<<<dim3(9), 256, 0, stream>>>(bq, bk, bv, bqkv);

    // 1. embedding + maxpool (bf16)
    k_embed<<<dim3(NTOK), dim3(256), 0, stream>>>(x, emb, h0b);
    k_maxpool<<<dim3(NTOK), dim3(256), 0, stream>>>(h0b, mpb);

    // 2. zero h1 (cols 256..767 stay zero = pad to NQ)
    hipMemsetAsync(h1f, 0, (size_t)NTOK*NQ_*4, stream);

    // 3. inception: fused 1x1 (inc1|inc3a|inc5a) + incp, all MFMA
    k_bgemm<0,0,false><<<gb(NTOK, 176, 1), 256, 0, stream>>>(
        h0b, wincat, CO, nullptr, binc, 1.f, 176, D_, D_, D_, 176, 0, 0, 0);
    k_bgemm<0,0,false><<<gb(NTOK, 32, 1), 256, 0, stream>>>(
        mpb, wincp, h1f + 224, nullptr, incp_b, 1.f, 32, D_, D_, D_, NQ_, 0, 0, 0);
    k_copy64<<<dim3(NTOK), dim3(64), 0, stream>>>(CO, h1f);
    k_conv3<<<dim3(NTOK), dim3(128), 0, stream>>>(CO, inc3b_w, inc3b_b, h1f);
    k_conv5<<<dim3(NTOK), dim3(64), 0, stream>>>(CO, inc5b_w, inc5b_b, h1f);

    // 4. quantum layers
    k_quantum<<<dim3(NTOK), dim3(256), 0, stream>>>(h1f, q_rot, q_ent, 0);
    k_quantum<<<dim3(NTOK), dim3(256), 0, stream>>>(h1f, q_rot, q_ent, 1);

    // 5. GNN
    k_t2b<<<dim3(24,32,2), 256, 0, stream>>>(h1f, h1t, S_, NQ_, (long)S_*NQ_, (long)S_*NQ_);
    k_bgemm<0,1,false><<<gb(S_, NQ_, B_), 256, 0, stream>>>(
        adjb, h1t, t1b, nullptr, nullptr, 1.f, NQ_, S_, S_, S_, NQ_,
        (long)S_*S_, (long)NQ_*S_, (long)S_*NQ_);
    k_bgemm<0,0,true><<<gb(NTOK, 384, 1), 256, 0, stream>>>(
        t1b, gw1t, gbf, nullptr, gnn_b1, 1.f, 384, D_, D_, D_, 384, 0, 0, 0);
    k_t2b<<<dim3(12,32,2), 256, 0, stream>>>(gbf, gt, S_, 384, (long)S_*384, (long)S_*384);
    k_bgemm<0,1,false><<<gb(S_, 384, B_), 256, 0, stream>>>(
        adjb, gt, t2bv, nullptr, nullptr, 1.f, 384, S_, S_, S_, 384,
        (long)S_*S_, (long)384*S_, (long)S_*384);
    k_bgemm<0,2,false><<<gb(NTOK, D_, 1), 256, 0, stream>>>(
        t2bv, gw2t, h2b, h2f, gnn_b2, 1.f, D_, 384, 384, 384, D_, 0, 0, 0);

    // 6. attention: fused QKV -> QK^T (bf16) -> masked softmax -> PV -> WO -> add+LN
    k_bgemm<0,5,false><<<gb(NTOK, 3*D_, 1), 256, 0, stream>>>(
        h2b, wqkvt, Qh, nullptr, bqkv, 1.f, 3*D_, D_, D_, D_, 0, 0, 0, 0);
    k_bgemm<0,1,false><<<gb(S_, S_, B_*H_), 256, 0, stream>>>(
        Qh, Kh, scob, nullptr, nullptr, 0.125f, S_, HD_, HD_, HD_, S_,
        (long)S_*HD_, (long)S_*HD_, (long)S_*S_);
    k_softmax<<<dim3(B_*H_*S_), dim3(256), 0, stream>>>(scob, Pb, amask);
    k_bgemm<0,1,false><<<gb(S_, HD_, B_*H_), 256, 0, stream>>>(
        Pb, Vt, ctxh, nullptr, nullptr, 1.f, HD_, S_, S_, S_, HD_,
        (long)S_*S_, (long)HD_*S_, (long)S_*HD_);
    k_bgemm<1,0,false><<<gb(NTOK, D_, 1), 256, 0, stream>>>(
        ctxh, wot, ao, nullptr, bo, 1.f, D_, D_, D_, D_, D_, 0, 0, 0);
    k_addln<<<dim3(NTOK), dim3(256), 0, stream>>>(h2f, ao, ln1_g, ln1_b, hlnf, hlnb);

    // 7. FFN
    k_bgemm<0,1,true><<<gb(NTOK, 4*D_, 1), 256, 0, stream>>>(
        hlnb, fw1t, ff1b, nullptr, ff_b1, 1.f, 4*D_, D_, D_, D_, 4*D_, 0, 0, 0);
    k_bgemm<0,0,false><<<gb(NTOK, D_, 1), 256, 0, stream>>>(
        ff1b, fw2t, ao2, nullptr, ff_b2, 1.f, D_, 4*D_, 4*D_, 4*D_, D_, 0, 0, 0);
    k_addln<<<dim3(NTOK), dim3(256), 0, stream>>>(hlnf, ao2, ln2_g, ln2_b, nullptr, hfb);

    // 8. heads: pool, vocab GEMM (256^2 ring-4 pipeline, overwrites all d_out scratch), task
    k_pool<<<dim3(B_*3), dim3(256), 0, stream>>>(hfb, pooled);
    k_vgemm<<<dim3(NTOK/256, V_/256, 1), dim3(512), 131072, stream>>>(
        hfb, owt, (float*)d_out, out_b, V_, D_, D_, D_, V_);
    k_task<<<dim3(1), dim3(64), 0, stream>>>(pooled, task_w, task_b, (float*)d_out);
}

// Round 8
// 835.590 us; speedup vs baseline: 6.9725x; 1.1074x over previous
//
#include <hip/hip_runtime.h>
#include <hip/hip_bf16.h>

#define B_ 2
#define S_ 1024
#define D_ 768
#define H_ 12
#define HD_ 64
#define V_ 32000
#define NQ_ 768
#define NTOK (B_*S_)
#define QKVS 1572864L   // shorts per Q/K/V segment [B,H,S,64]

typedef __attribute__((ext_vector_type(8))) short short8;
typedef __attribute__((ext_vector_type(4))) float f32x4;

typedef const __attribute__((address_space(1))) void* as1vp;
typedef __attribute__((address_space(3))) void* as3vp;

__device__ __forceinline__ short f2bf(float f) {
    union { float f; unsigned u; } v; v.f = f;
    unsigned r = (v.u + 0x7FFFu + ((v.u >> 16) & 1u)) >> 16;
    return (short)r;
}
__device__ __forceinline__ float b2fs(short s) {
    union { unsigned u; float f; } v; v.u = ((unsigned)(unsigned short)s) << 16;
    return v.f;
}

// ---------------- embedding -> bf16 ----------------
__global__ void k_embed(const int* __restrict__ x, const float* __restrict__ emb,
                        short* __restrict__ h0b) {
    int n = blockIdx.x;
    int row = x[n];
    for (int d = threadIdx.x; d < D_; d += blockDim.x)
        h0b[(long)n*D_ + d] = f2bf(emb[(long)row*D_ + d]);
}

// ---------------- maxpool3 over sequence (bf16 in/out) ----------------
__global__ void k_maxpool(const short* __restrict__ h0b, short* __restrict__ mpb) {
    int n = blockIdx.x; int s = n % S_;
    for (int d = threadIdx.x; d < D_; d += blockDim.x) {
        float m = b2fs(h0b[(long)n*D_ + d]);
        if (s > 0)      m = fmaxf(m, b2fs(h0b[(long)(n-1)*D_ + d]));
        if (s < S_-1)   m = fmaxf(m, b2fs(h0b[(long)(n+1)*D_ + d]));
        mpb[(long)n*D_ + d] = f2bf(m);
    }
}

// ---------------- fused conv3+conv5+copy+incp-merge+quantum x2 ----------------
// One block per token row. CO = [NTOK,176] f32 (1x1 outputs: 64|96|16).
// h1f cols 224..255 already hold incp output; writes the full 768-wide row.
__global__ __launch_bounds__(256) void k_mix(
    const float* __restrict__ CO, const float* __restrict__ c3w,
    const float* __restrict__ c3b, const float* __restrict__ c5w,
    const float* __restrict__ c5b, const float* __restrict__ q_rot,
    const float* __restrict__ q_ent, float* __restrict__ h1f)
{
    __shared__ float co[5][176];
    __shared__ float ta[NQ_];
    __shared__ float tb[NQ_];
    int n = blockIdx.x; int s = n & (S_-1);
    int t = threadIdx.x;
    for (int idx = t; idx < 5*176; idx += 256) {
        int dr = idx / 176 - 2, c = idx % 176;
        int ss = s + dr;
        co[idx/176][c] = (ss >= 0 && ss < S_) ? CO[(long)(n + dr)*176 + c] : 0.f;
    }
    for (int d = 256 + t; d < NQ_; d += 256) ta[d] = 0.f;
    __syncthreads();
    if (t < 64) {
        ta[t] = co[2][t];                      // inc1 passthrough
    } else if (t < 192) {
        int o = t - 64;                        // conv3: 96->128, pad 1
        float acc = c3b[o];
        #pragma unroll
        for (int k = 0; k < 3; k++)
            for (int i = 0; i < 96; i++)
                acc += co[1+k][64+i] * c3w[(o*96+i)*3 + k];
        ta[t] = acc;
    } else if (t < 224) {
        int o = t - 192;                       // conv5: 16->32, pad 2
        float acc = c5b[o];
        #pragma unroll
        for (int k = 0; k < 5; k++)
            for (int i = 0; i < 16; i++)
                acc += co[k][160+i] * c5w[(o*16+i)*5 + k];
        ta[t] = acc;
    } else {
        ta[t] = h1f[(long)n*NQ_ + t];          // incp output cols 224..255
    }
    __syncthreads();
    #pragma unroll
    for (int layer = 0; layer < 2; layer++) {
        const float* rot = q_rot + (long)layer*NQ_*3;
        const float* ent = q_ent + (long)layer*(NQ_-1);
        for (int q = t; q < NQ_; q += 256) {
            float hv = ta[q];
            tb[q] = __sinf(hv + rot[q*3]) + __sinf(hv + rot[q*3+1]) + __sinf(hv + rot[q*3+2]);
        }
        __syncthreads();
        for (int q = t; q < NQ_; q += 256) {
            float v;
            if (q == NQ_-1) v = 0.f;
            else {
                int qm = (q == 0) ? (NQ_-1) : (q-1);
                v = tb[q]*__sinf(ent[q]) + tb[qm]*__cosf(ent[q]);
            }
            ta[q] = v;
        }
        __syncthreads();
    }
    for (int q = t; q < NQ_; q += 256) h1f[(long)n*NQ_ + q] = ta[q];
}

// ---------------- bf16 MFMA GEMM (128x128, 2-phase, optional split-K) ----------------
// A [M,K] bf16 row-major (AMODE=1: head-major [B,H,S,64] read as [NTOK,768]).
// B [N,K] bf16 row-major. Tile 128x128, BK=32, 4 waves 2x2.
// OMODE: 0=f32, 1=bf16, 2=dual, 5=fused-QKV routing (Cv=Qh base).
// KSPLIT>1 (unbatched, OMODE0, no RELU): z=kz, atomicAdd partials, bias on kz==0.
template<int AMODE, int OMODE, bool RELU, int KSPLIT = 1>
__global__ __launch_bounds__(256) void k_bgemm(
    const short* __restrict__ A, const short* __restrict__ Bm,
    void* __restrict__ Cv, float* __restrict__ C2,
    const float* __restrict__ bias, float scale,
    int N, int K, int lda, int ldb, int ldc,
    long sA, long sB, long sC)
{
    __shared__ short lds[2][8192];   // per buf: A shorts [0,4096), B [4096,8192)
    const int t = threadIdx.x;
    const int lane = t & 63, wave = t >> 6;
    const int wm = wave >> 1, wn = wave & 1;
    const int l15 = lane & 15, l4 = lane >> 4;

    int bx = blockIdx.x, by = blockIdx.y;
    if (KSPLIT == 1 && gridDim.z == 1) {   // XCD-chunked bijective remap (T1)
        int lin = by * gridDim.x + bx;
        int nwg = gridDim.x * gridDim.y;
        int xcd = lin & 7, pos = lin >> 3;
        int q = nwg >> 3, r = nwg & 7;
        int lin2 = (xcd < r ? xcd*(q+1) : r*(q+1) + (xcd-r)*q) + pos;
        bx = lin2 % gridDim.x;
        by = lin2 / gridDim.x;
    }
    const int tile_m = bx * 128, tile_n = by * 128;
    const int kz = (KSPLIT > 1) ? blockIdx.z : 0;
    const int Keff = K / KSPLIT;
    const int kbase = kz * Keff;
    const long aoff = (KSPLIT > 1) ? 0 : (long)blockIdx.z * sA;
    const long boff = (KSPLIT > 1) ? 0 : (long)blockIdx.z * sB;
    const long coff = (KSPLIT > 1) ? 0 : (long)blockIdx.z * sC;

    const int cA0 = t, cA1 = t + 256;
    const int arow0 = tile_m + ((cA0 >> 6) << 4) + (cA0 & 15);
    const int arow1 = tile_m + ((cA1 >> 6) << 4) + (cA1 & 15);
    const int akb0 = ((cA0 >> 4) & 3) * 8;
    const int akb1 = ((cA1 >> 4) & 3) * 8;
    const int bcol0 = tile_n + (((cA0 >> 4) & 7) << 4) + (cA0 & 15);
    const int bcol1 = tile_n + (((cA1 >> 4) & 7) << 4) + (cA1 & 15);
    const int bkb0 = (cA0 >> 7) * 8;
    const int bkb1 = (cA1 >> 7) * 8;
    const short* bp0 = Bm + boff + (long)bcol0*ldb + bkb0 + kbase;
    const short* bp1 = Bm + boff + (long)bcol1*ldb + bkb1 + kbase;
    const short* ap0 = nullptr; const short* ap1 = nullptr;
    long abase0 = 0, abase1 = 0;
    if (AMODE == 0) {
        ap0 = A + aoff + (long)arow0*lda + akb0 + kbase;
        ap1 = A + aoff + (long)arow1*lda + akb1 + kbase;
    } else {
        abase0 = ((long)((arow0 >> 10)*H_) * S_ + (arow0 & (S_-1))) * 64;
        abase1 = ((long)((arow1 >> 10)*H_) * S_ + (arow1 & (S_-1))) * 64;
    }
    const int wb = wave * 1024;

    auto stage = [&](int buf, int k0) {
        char* lb = (char*)&lds[buf][0];
        const short *a0, *a1;
        if (AMODE == 0) { a0 = ap0 + k0; a1 = ap1 + k0; }
        else {
            int ka0 = kbase + k0 + akb0, ka1 = kbase + k0 + akb1;
            a0 = A + abase0 + (long)(ka0 >> 6)*(S_*64) + (ka0 & 63);
            a1 = A + abase1 + (long)(ka1 >> 6)*(S_*64) + (ka1 & 63);
        }
        __builtin_amdgcn_global_load_lds((as1vp)a0,          (as3vp)(lb + wb),          16, 0, 0);
        __builtin_amdgcn_global_load_lds((as1vp)a1,          (as3vp)(lb + 4096 + wb),   16, 0, 0);
        __builtin_amdgcn_global_load_lds((as1vp)(bp0 + k0),  (as3vp)(lb + 8192 + wb),   16, 0, 0);
        __builtin_amdgcn_global_load_lds((as1vp)(bp1 + k0),  (as3vp)(lb + 12288 + wb),  16, 0, 0);
    };

    f32x4 acc[4][4] = {};
    const int nk = Keff >> 5;
    stage(0, 0);
    __syncthreads();
    int cur = 0;
    for (int ks = 0; ks < nk; ks++) {
        if (ks + 1 < nk) stage(cur ^ 1, (ks + 1) << 5);
        short8 af[4], bfv[4];
        const short* lb = &lds[cur][0];
        #pragma unroll
        for (int m = 0; m < 4; m++)
            af[m] = *(const short8*)(lb + (wm*4 + m)*512 + l4*128 + l15*8);
        #pragma unroll
        for (int n = 0; n < 4; n++)
            bfv[n] = *(const short8*)(lb + 4096 + l4*1024 + (wn*4 + n)*128 + l15*8);
        #pragma unroll
        for (int m = 0; m < 4; m++)
            #pragma unroll
            for (int n = 0; n < 4; n++)
                acc[m][n] = __builtin_amdgcn_mfma_f32_16x16x32_bf16(af[m], bfv[n], acc[m][n], 0, 0, 0);
        __syncthreads();
        cur ^= 1;
    }

    #pragma unroll
    for (int m = 0; m < 4; m++) {
        #pragma unroll
        for (int n = 0; n < 4; n++) {
            int col = tile_n + wn*64 + n*16 + l15;
            if (col >= N) continue;
            float bv = (bias && (KSPLIT == 1 || kz == 0)) ? bias[col] : 0.f;
            #pragma unroll
            for (int r = 0; r < 4; r++) {
                int row = tile_m + wm*64 + m*16 + l4*4 + r;
                float v = acc[m][n][r] * scale + bv;
                if (RELU) v = fmaxf(v, 0.f);
                if (OMODE == 0) {
                    if (KSPLIT > 1)
                        atomicAdd(&((float*)Cv)[(long)row*ldc + col], v);
                    else
                        ((float*)Cv)[coff + (long)row*ldc + col] = v;
                } else if (OMODE == 1) {
                    ((short*)Cv)[coff + (long)row*ldc + col] = f2bf(v);
                } else if (OMODE == 2) {
                    C2[coff + (long)row*ldc + col] = v;
                    ((short*)Cv)[coff + (long)row*ldc + col] = f2bf(v);
                } else {   // OMODE 5: fused QKV routing
                    int seg = (col >= 1536) ? 2 : ((col >= 768) ? 1 : 0);
                    int c = col - seg*768;
                    int hh = c >> 6, dd = c & 63;
                    int b = row >> 10, s = row & (S_-1);
                    long hidx = (long)(b*H_ + hh);
                    short* base = (short*)Cv;
                    if (seg < 2) base[(long)seg*QKVS + (hidx*S_ + s)*64 + dd] = f2bf(v);
                    else         base[2L*QKVS + (hidx*64 + dd)*S_ + s] = f2bf(v);
                }
            }
        }
    }
}

// ---------------- 256x256 ring-5 depth-3 counted-vmcnt MFMA GEMM (vocab) ----------------
// A [M,K] bf16 (M%256==0), B [N,K] bf16 (N%256==0), K%32==0, K>=128.
// 512 threads = 8 waves. LDS: ring of 5 BK=32 regions (A 16KB + B 16KB each) = 160 KiB.
// Per k-step: issue stage(s+3) -> vmcnt(12) -> barrier -> 12 ds_read_b128 -> 32 MFMA.
// Hazard: stage(s+3) targets region (s-2)%5; its reads completed before barrier(s-1),
// which every wave in iter s has passed -> race-free. Depth-3 covers ~3 steps (~1100cyc)
// of load latency vs ~900cyc HBM miss.
__global__ __launch_bounds__(512, 1) void k_vgemm(
    const short* __restrict__ A, const short* __restrict__ Bm,
    float* __restrict__ C, const float* __restrict__ bias,
    int N, int K, int lda, int ldb, int ldc)
{
    extern __shared__ short lds[];   // 81920 shorts = 160 KiB
    const int t = threadIdx.x;
    const int lane = t & 63, wave = t >> 6;
    const int wm = wave >> 2, wn = wave & 3;
    const int l15 = lane & 15, l4 = lane >> 4;
    int bx = blockIdx.x, by = blockIdx.y;
    {   // XCD-chunked bijective swizzle
        int lin = by * gridDim.x + bx;
        int nwg = gridDim.x * gridDim.y;
        int xcd = lin & 7, pos = lin >> 3;
        int q = nwg >> 3, r = nwg & 7;
        int lin2 = (xcd < r ? xcd*(q+1) : r*(q+1) + (xcd-r)*q) + pos;
        bx = lin2 % gridDim.x; by = lin2 / gridDim.x;
    }
    const int tile_m = bx * 256, tile_n = by * 256;

    const int c0 = wave*128 + lane;
    const int c1 = c0 + 64;
    const int ar0 = ((c0 >> 6) << 4) + (c0 & 15), ak0 = ((c0 >> 4) & 3) << 3;
    const int ar1 = ((c1 >> 6) << 4) + (c1 & 15), ak1 = ((c1 >> 4) & 3) << 3;
    const short* pa0 = A + (long)(tile_m + ar0)*lda + ak0;
    const short* pa1 = A + (long)(tile_m + ar1)*lda + ak1;
    const short* pb0 = Bm + (long)(tile_n + ar0)*ldb + ak0;
    const short* pb1 = Bm + (long)(tile_n + ar1)*ldb + ak1;
    char* lb = (char*)lds;
    const int wb0 = wave*2048, wb1 = wave*2048 + 1024;

    auto stage = [&](int reg, int s) {
        int k = s << 5;
        char* ab = lb + reg*32768;
        __builtin_amdgcn_global_load_lds((as1vp)(pa0 + k), (as3vp)(ab + wb0),         16, 0, 0);
        __builtin_amdgcn_global_load_lds((as1vp)(pa1 + k), (as3vp)(ab + wb1),         16, 0, 0);
        __builtin_amdgcn_global_load_lds((as1vp)(pb0 + k), (as3vp)(ab + 16384 + wb0), 16, 0, 0);
        __builtin_amdgcn_global_load_lds((as1vp)(pb1 + k), (as3vp)(ab + 16384 + wb1), 16, 0, 0);
    };

    f32x4 acc[8][4] = {};
    const int nks = K >> 5;
    stage(0, 0); stage(1, 1); stage(2, 2);
    const int ard = ((wm*8) << 10) + (l4 << 8) + l15*16;          // + fr<<10
    const int brd = 16384 + ((wn*4) << 10) + (l4 << 8) + l15*16;  // + fc<<10

    int reg = 0;
    for (int s = 0; s < nks; s++) {
        if (s + 3 < nks) {
            int r3 = reg + 3; if (r3 >= 5) r3 -= 5;
            stage(r3, s + 3);
        }
        if (s < nks - 3)       asm volatile("s_waitcnt vmcnt(12)" ::: "memory");
        else if (s == nks - 3) asm volatile("s_waitcnt vmcnt(8)"  ::: "memory");
        else if (s == nks - 2) asm volatile("s_waitcnt vmcnt(4)"  ::: "memory");
        else                   asm volatile("s_waitcnt vmcnt(0)"  ::: "memory");
        __builtin_amdgcn_s_barrier();
        const char* rb = lb + reg*32768;
        short8 a[8], b[4];
        #pragma unroll
        for (int fr = 0; fr < 8; fr++) a[fr] = *(const short8*)(rb + ard + (fr << 10));
        #pragma unroll
        for (int fc = 0; fc < 4; fc++) b[fc] = *(const short8*)(rb + brd + (fc << 10));
        __builtin_amdgcn_s_setprio(1);
        #pragma unroll
        for (int fr = 0; fr < 8; fr++)
            #pragma unroll
            for (int fc = 0; fc < 4; fc++)
                acc[fr][fc] = __builtin_amdgcn_mfma_f32_16x16x32_bf16(a[fr], b[fc], acc[fr][fc], 0, 0, 0);
        __builtin_amdgcn_s_setprio(0);
        if (++reg == 5) reg = 0;
    }

    #pragma unroll
    for (int fr = 0; fr < 8; fr++) {
        #pragma unroll
        for (int fc = 0; fc < 4; fc++) {
            int col = tile_n + wn*64 + fc*16 + l15;
            float bv = bias ? bias[col] : 0.f;
            #pragma unroll
            for (int rr = 0; rr < 4; rr++) {
                int row = tile_m + wm*128 + fr*16 + l4*4 + rr;
                C[(long)row*ldc + col] = acc[fr][fc][rr] + bv;
            }
        }
    }
}

// ---------------- f32 -> bf16 convert ----------------
__global__ void k_f2b(const float* __restrict__ in, short* __restrict__ out, long n) {
    long i = ((long)blockIdx.x*256 + threadIdx.x)*4;
    if (i >= n) return;
    f32x4 v = *(const f32x4*)(in + i);
    out[i+0] = f2bf(v.x); out[i+1] = f2bf(v.y); out[i+2] = f2bf(v.z); out[i+3] = f2bf(v.w);
}

// ---------------- f32 [R,C] -> bf16 [C,R] transpose-convert (batched, opt. relu) ----------------
template<bool RELU>
__global__ void k_t2b(const float* __restrict__ in, short* __restrict__ out,
                      int R, int C, long sIn, long sOut) {
    __shared__ float tile[32][33];
    int bc = blockIdx.x * 32, br = blockIdx.y * 32;
    const float* ip = in + (long)blockIdx.z * sIn;
    short* op = out + (long)blockIdx.z * sOut;
    int tx = threadIdx.x & 31, ty = threadIdx.x >> 5;   // 256 threads
    #pragma unroll
    for (int i = 0; i < 32; i += 8)
        tile[ty + i][tx] = ip[(long)(br + ty + i)*C + bc + tx];
    __syncthreads();
    #pragma unroll
    for (int i = 0; i < 32; i += 8) {
        float v = tile[tx][ty + i];
        if (RELU) v = fmaxf(v, 0.f);
        op[(long)(bc + ty + i)*R + br + tx] = f2bf(v);
    }
}

// ---------------- bias concat: qkv [2304] ----------------
__global__ void k_bqkv(const float* __restrict__ bq, const float* __restrict__ bk,
                       const float* __restrict__ bv, float* __restrict__ out) {
    int i = blockIdx.x*256 + threadIdx.x;
    if (i >= 2304) return;
    out[i] = (i < 768) ? bq[i] : (i < 1536 ? bk[i-768] : bv[i-1536]);
}

// ---------------- bias concat: inception [176] ----------------
__global__ void k_binc(const float* __restrict__ b1, const float* __restrict__ b3,
                       const float* __restrict__ b5, float* __restrict__ out) {
    int i = threadIdx.x;
    if (i >= 176) return;
    out[i] = (i < 64) ? b1[i] : (i < 160 ? b3[i-64] : b5[i-160]);
}

// ---------------- masked softmax: bf16 scores -> bf16 P ----------------
__global__ __launch_bounds__(256) void k_softmax(const short* __restrict__ sc,
                                                 short* __restrict__ P,
                                                 const int* __restrict__ mask) {
    __shared__ float red[256];
    long row = blockIdx.x;                 // z*S + q, z = b*H + h
    int b = (int)(row >> 10) / H_;
    const short* r = sc + row * S_;
    short* pr = P + row * S_;
    const int* mrow = mask + b * S_;
    int t = threadIdx.x;
    float v[4]; float mx = -1e30f;
    #pragma unroll
    for (int kk = 0; kk < 4; kk++) {
        int k = kk*256 + t;
        float s = b2fs(r[k]);
        if (mrow[k] == 1) s = -1e9f;
        v[kk] = s; mx = fmaxf(mx, s);
    }
    red[t] = mx; __syncthreads();
    for (int off = 128; off > 0; off >>= 1) {
        if (t < off) red[t] = fmaxf(red[t], red[t+off]);
        __syncthreads();
    }
    mx = red[0]; __syncthreads();
    float sum = 0.f;
    #pragma unroll
    for (int kk = 0; kk < 4; kk++) { v[kk] = expf(v[kk] - mx); sum += v[kk]; }
    red[t] = sum; __syncthreads();
    for (int off = 128; off > 0; off >>= 1) {
        if (t < off) red[t] += red[t+off];
        __syncthreads();
    }
    float inv = 1.f / red[0];
    #pragma unroll
    for (int kk = 0; kk < 4; kk++) pr[kk*256 + t] = f2bf(v[kk] * inv);
}

// ---------------- residual add + LayerNorm (f32 out optional + bf16 out) ----------------
__global__ void k_addln(const float* __restrict__ a, const float* __restrict__ bvec,
                        const float* __restrict__ g, const float* __restrict__ be,
                        float* __restrict__ outf, short* __restrict__ outb) {
    __shared__ float row[D_];
    __shared__ float red[256];
    int n = blockIdx.x, t = threadIdx.x;
    float lsum = 0.f;
    for (int d = t; d < D_; d += 256) {
        float v = a[(long)n*D_ + d] + bvec[(long)n*D_ + d];
        row[d] = v; lsum += v;
    }
    red[t] = lsum; __syncthreads();
    for (int off = 128; off > 0; off >>= 1) {
        if (t < off) red[t] += red[t+off];
        __syncthreads();
    }
    float mean = red[0] / D_; __syncthreads();
    float lvar = 0.f;
    for (int d = t; d < D_; d += 256) { float v = row[d]-mean; lvar += v*v; }
    red[t] = lvar; __syncthreads();
    for (int off = 128; off > 0; off >>= 1) {
        if (t < off) red[t] += red[t+off];
        __syncthreads();
    }
    float rstd = rsqrtf(red[0]/D_ + 1e-5f);
    for (int d = t; d < D_; d += 256) {
        float v = (row[d]-mean)*rstd*g[d] + be[d];
        if (outf) outf[(long)n*D_ + d] = v;
        outb[(long)n*D_ + d] = f2bf(v);
    }
}

// ---------------- mean-pool over sequence (bf16 in) ----------------
__global__ void k_pool(const short* __restrict__ h, float* __restrict__ pooled) {
    int b = blockIdx.x / 3;
    int d = (blockIdx.x % 3)*256 + threadIdx.x;
    float s = 0.f;
    for (int ss = 0; ss < S_; ss++) s += b2fs(h[(long)(b*S_ + ss)*D_ + d]);
    pooled[b*D_ + d] = s * (1.f/S_);
}

// ---------------- task head (6 outputs, f32) ----------------
__global__ void k_task(const float* __restrict__ pooled, const float* __restrict__ tw,
                       const float* __restrict__ tb, float* __restrict__ out) {
    int i = threadIdx.x;
    if (i >= 6) return;
    int b = i/3, j = i%3;
    float acc = tb[j];
    for (int d = 0; d < D_; d++) acc += pooled[b*D_ + d]*tw[d*3 + j];
    out[(long)NTOK*V_ + i] = acc;
}

extern "C" void kernel_launch(void* const* d_in, const int* in_sizes, int n_in,
                              void* d_out, int out_size, void* d_ws, size_t ws_size,
                              hipStream_t stream) {
    const int*   x      = (const int*)d_in[0];
    const int*   amask  = (const int*)d_in[1];
    const float* adj    = (const float*)d_in[2];
    const float* emb    = (const float*)d_in[3];
    const float* inc1_w = (const float*)d_in[4];  const float* inc1_b = (const float*)d_in[5];
    const float* inc3a_w= (const float*)d_in[6];  const float* inc3a_b= (const float*)d_in[7];
    const float* inc3b_w= (const float*)d_in[8];  const float* inc3b_b= (const float*)d_in[9];
    const float* inc5a_w= (const float*)d_in[10]; const float* inc5a_b= (const float*)d_in[11];
    const float* inc5b_w= (const float*)d_in[12]; const float* inc5b_b= (const float*)d_in[13];
    const float* incp_w = (const float*)d_in[14]; const float* incp_b = (const float*)d_in[15];
    const float* q_rot  = (const float*)d_in[16]; const float* q_ent  = (const float*)d_in[17];
    const float* gnn_w1 = (const float*)d_in[18]; const float* gnn_b1 = (const float*)d_in[19];
    const float* gnn_w2 = (const float*)d_in[20]; const float* gnn_b2 = (const float*)d_in[21];
    const float* wq = (const float*)d_in[22]; const float* bq = (const float*)d_in[23];
    const float* wk = (const float*)d_in[24]; const float* bk = (const float*)d_in[25];
    const float* wv = (const float*)d_in[26]; const float* bv = (const float*)d_in[27];
    const float* wo = (const float*)d_in[28]; const float* bo = (const float*)d_in[29];
    const float* ff_w1 = (const float*)d_in[30]; const float* ff_b1 = (const float*)d_in[31];
    const float* ff_w2 = (const float*)d_in[32]; const float* ff_b2 = (const float*)d_in[33];
    const float* ln1_g = (const float*)d_in[34]; const float* ln1_b = (const float*)d_in[35];
    const float* ln2_g = (const float*)d_in[36]; const float* ln2_b = (const float*)d_in[37];
    const float* out_w = (const float*)d_in[38]; const float* out_b = (const float*)d_in[39];
    const float* task_w= (const float*)d_in[40]; const float* task_b= (const float*)d_in[41];

    // ---- d_out arena (f32 slot offsets; non-overlapping; dead before vocab GEMM) ----
    float* F = (float*)d_out;
    short* wqkvt = (short*)(F + 0L);
    short* wot   = (short*)(F + 884736L);
    short* gw1t  = (short*)(F + 1179648L);
    short* gw2t  = (short*)(F + 1327104L);
    short* fw1t  = (short*)(F + 1474560L);
    short* fw2t  = (short*)(F + 2654208L);
    short* wincat= (short*)(F + 3833856L);
    short* wincp = (short*)(F + 3950592L);
    float* binc  = F + 4012032L;
    float* bqkv  = F + 4012288L;
    short* adjb  = (short*)(F + 4014592L);
    short* h0b   = (short*)(F + 5063168L);
    short* mpb   = (short*)(F + 5849600L);
    float* CO    = F + 6636032L;
    float* h1f   = F + 6996480L;
    short* h1t   = (short*)(F + 8569344L);
    short* t1b   = (short*)(F + 9355776L);
    float* gbf   = F + 10142208L;
    short* gt    = (short*)(F + 10928640L);
    short* t2bv  = (short*)(F + 11321856L);
    float* h2f   = F + 11715072L;
    short* h2b   = (short*)(F + 13287936L);
    short* Qh    = (short*)(F + 14074368L);    // Kh, Vt contiguous (OMODE5)
    short* Kh    = (short*)(F + 14860800L);
    short* Vt    = (short*)(F + 15647232L);    // +pad for PV B-OOB
    short* ctxh  = (short*)(F + 16499200L);
    float* ao    = F + 17285632L;
    float* hlnf  = F + 18858496L;
    short* hlnb  = (short*)(F + 20431360L);
    short* ff1b  = (short*)(F + 21217792L);
    float* ao2   = F + 24363520L;
    short* scob  = (short*)(F + 25936384L);    // bf16 scores [B*H,S,S]
    short* Pb    = (short*)(F + 51102208L);

    // ---- d_ws (>= 58.6 MB proven): buffers read during the vocab GEMM ----
    char* W = (char*)d_ws;
    short* hfb    = (short*)(W + 0);
    float* pooled = (float*)(W + 3145728);
    short* owt    = (short*)(W + 3151872);     // [32000x768] bf16

    auto gb = [](int M, int N, int Z) { return dim3((unsigned)(M/128), (unsigned)((N+127)/128), (unsigned)Z); };

    hipFuncSetAttribute((const void*)k_vgemm, hipFuncAttributeMaxDynamicSharedMemorySize, 163840);

    // 0a. zero split-K accumulators
    hipMemsetAsync(gbf, 0, (size_t)NTOK*384*4, stream);
    hipMemsetAsync(ao,  0, (size_t)NTOK*D_*4, stream);
    hipMemsetAsync(ao2, 0, (size_t)NTOK*D_*4, stream);

    // 0b. one-time converts/transposes
    k_t2b<false><<<dim3(24,24,1), 256, 0, stream>>>(wq, wqkvt,             D_, D_, 0, 0);
    k_t2b<false><<<dim3(24,24,1), 256, 0, stream>>>(wk, wqkvt + 768*768,   D_, D_, 0, 0);
    k_t2b<false><<<dim3(24,24,1), 256, 0, stream>>>(wv, wqkvt + 2*768*768, D_, D_, 0, 0);
    k_t2b<false><<<dim3(24,24,1), 256, 0, stream>>>(wo, wot, D_, D_, 0, 0);
    k_t2b<false><<<dim3(12,24,1), 256, 0, stream>>>(gnn_w1, gw1t, D_, 384, 0, 0);
    k_t2b<false><<<dim3(24,12,1), 256, 0, stream>>>(gnn_w2, gw2t, 384, D_, 0, 0);
    k_t2b<false><<<dim3(96,24,1), 256, 0, stream>>>(ff_w1, fw1t, D_, 4*D_, 0, 0);
    k_t2b<false><<<dim3(24,96,1), 256, 0, stream>>>(ff_w2, fw2t, 4*D_, D_, 0, 0);
    k_t2b<false><<<dim3(1000,24,1), 256, 0, stream>>>(out_w, owt, D_, V_, 0, 0);
    k_f2b<<<dim3(2048), 256, 0, stream>>>(adj, adjb, (long)B_*S_*S_);
    k_f2b<<<dim3(48), 256, 0, stream>>>(inc1_w,  wincat,           64*768);
    k_f2b<<<dim3(72), 256, 0, stream>>>(inc3a_w, wincat + 64*768,  96*768);
    k_f2b<<<dim3(12), 256, 0, stream>>>(inc5a_w, wincat + 160*768, 16*768);
    k_f2b<<<dim3(24), 256, 0, stream>>>(incp_w,  wincp,            32*768);
    k_binc<<<dim3(1), 256, 0, stream>>>(inc1_b, inc3a_b, inc5a_b, binc);
    k_bqkv<<<dim3(9), 256, 0, stream>>>(bq, bk, bv, bqkv);

    // 1. embedding + maxpool (bf16)
    k_embed<<<dim3(NTOK), dim3(256), 0, stream>>>(x, emb, h0b);
    k_maxpool<<<dim3(NTOK), dim3(256), 0, stream>>>(h0b, mpb);

    // 2. inception 1x1 GEMMs (fused 176-wide + incp to h1f cols 224..255)
    k_bgemm<0,0,false><<<gb(NTOK, 176, 1), 256, 0, stream>>>(
        h0b, wincat, CO, nullptr, binc, 1.f, 176, D_, D_, D_, 176, 0, 0, 0);
    k_bgemm<0,0,false><<<gb(NTOK, 32, 1), 256, 0, stream>>>(
        mpb, wincp, h1f + 224, nullptr, incp_b, 1.f, 32, D_, D_, D_, NQ_, 0, 0, 0);

    // 3. fused conv3/conv5/copy/quantum x2
    k_mix<<<dim3(NTOK), dim3(256), 0, stream>>>(
        CO, inc3b_w, inc3b_b, inc5b_w, inc5b_b, q_rot, q_ent, h1f);

    // 4. GNN
    k_t2b<false><<<dim3(24,32,2), 256, 0, stream>>>(h1f, h1t, S_, NQ_, (long)S_*NQ_, (long)S_*NQ_);
    k_bgemm<0,1,false><<<gb(S_, NQ_, B_), 256, 0, stream>>>(
        adjb, h1t, t1b, nullptr, nullptr, 1.f, NQ_, S_, S_, S_, NQ_,
        (long)S_*S_, (long)NQ_*S_, (long)S_*NQ_);
    k_bgemm<0,0,false,4><<<gb(NTOK, 384, 4), 256, 0, stream>>>(      // split-K=4, relu deferred
        t1b, gw1t, gbf, nullptr, gnn_b1, 1.f, 384, D_, D_, D_, 384, 0, 0, 0);
    k_t2b<true><<<dim3(12,32,2), 256, 0, stream>>>(gbf, gt, S_, 384, (long)S_*384, (long)S_*384);
    k_bgemm<0,1,false><<<gb(S_, 384, B_), 256, 0, stream>>>(
        adjb, gt, t2bv, nullptr, nullptr, 1.f, 384, S_, S_, S_, 384,
        (long)S_*S_, (long)384*S_, (long)S_*384);
    k_bgemm<0,2,false><<<gb(NTOK, D_, 1), 256, 0, stream>>>(
        t2bv, gw2t, h2b, h2f, gnn_b2, 1.f, D_, 384, 384, 384, D_, 0, 0, 0);

    // 5. attention: fused QKV -> QK^T (bf16) -> masked softmax -> PV -> WO -> add+LN
    k_bgemm<0,5,false><<<gb(NTOK, 3*D_, 1), 256, 0, stream>>>(
        h2b, wqkvt, Qh, nullptr, bqkv, 1.f, 3*D_, D_, D_, D_, 0, 0, 0, 0);
    k_bgemm<0,1,false><<<gb(S_, S_, B_*H_), 256, 0, stream>>>(
        Qh, Kh, scob, nullptr, nullptr, 0.125f, S_, HD_, HD_, HD_, S_,
        (long)S_*HD_, (long)S_*HD_, (long)S_*S_);
    k_softmax<<<dim3(B_*H_*S_), dim3(256), 0, stream>>>(scob, Pb, amask);
    k_bgemm<0,1,false><<<gb(S_, HD_, B_*H_), 256, 0, stream>>>(
        Pb, Vt, ctxh, nullptr, nullptr, 1.f, HD_, S_, S_, S_, HD_,
        (long)S_*S_, (long)HD_*S_, (long)S_*HD_);
    k_bgemm<1,0,false,2><<<gb(NTOK, D_, 2), 256, 0, stream>>>(       // split-K=2
        ctxh, wot, ao, nullptr, bo, 1.f, D_, D_, D_, D_, D_, 0, 0, 0);
    k_addln<<<dim3(NTOK), dim3(256), 0, stream>>>(h2f, ao, ln1_g, ln1_b, hlnf, hlnb);

    // 6. FFN
    k_bgemm<0,1,true><<<gb(NTOK, 4*D_, 1), 256, 0, stream>>>(
        hlnb, fw1t, ff1b, nullptr, ff_b1, 1.f, 4*D_, D_, D_, D_, 4*D_, 0, 0, 0);
    k_bgemm<0,0,false,4><<<gb(NTOK, D_, 4), 256, 0, stream>>>(       // split-K=4
        ff1b, fw2t, ao2, nullptr, ff_b2, 1.f, D_, 4*D_, 4*D_, 4*D_, D_, 0, 0, 0);
    k_addln<<<dim3(NTOK), dim3(256), 0, stream>>>(hlnf, ao2, ln2_g, ln2_b, nullptr, hfb);

    // 7. heads: pool, vocab GEMM (256^2 ring-5 depth-3), task
    k_pool<<<dim3(B_*3), dim3(256), 0, stream>>>(hfb, pooled);
    k_vgemm<<<dim3(NTOK/256, V_/256, 1), dim3(512), 163840, stream>>>(
        hfb, owt, (float*)d_out, out_b, V_, D_, D_, D_, V_);
    k_task<<<dim3(1), dim3(64), 0, stream>>>(pooled, task_w, task_b, (float*)d_out);
}